// Round 10
// baseline (89.719 us; speedup 1.0000x reference)
//
#include <hip/hip_runtime.h>

#define NPTS 4096
#define NEDGE 8064
#define M0f 0.05f
#define KMAXD2 7938
#define IDCAP 90          // basin-id clamp; triangular pair table needs IDCAP*(IDCAP-1)/2 <= 4096
#define SORTCAP 512       // in-wave sort capacity (8 regs/lane x 64 lanes)
#define PAIRCAP 160

// ---- ws byte offsets ----
#define F_OFF   0         // float[2][4096]
#define BAS_OFF 32768     // int[2][4096]
#define MU_OFF  65536     // float[2][128]
#define MV_OFF  66560     // int[2][128]
#define MM_OFF  67584     // uint[2][2]  (min,max bits)
#define NP_OFF  67600     // int[2]
#define PR_OFF  67616     // float2[2][PAIRCAP]

typedef unsigned long long u64;

__device__ inline float waveSum(float x) {
  for (int m = 32; m >= 1; m >>= 1) x += __shfl_xor(x, m);
  return x;
}

__device__ inline int isqrt_i(int x) {  // exact floor sqrt for 0 <= x < 2^20
  int r = (int)sqrtf((float)x);
  if ((r + 1) * (r + 1) <= x) r++;
  else if (r * r > x) r--;
  return r;
}

__device__ inline u64 shfl_xor64(u64 x, int m) {
  int lo = __shfl_xor((int)(unsigned)(x & 0xffffffffull), m);
  int hi = __shfl_xor((int)(unsigned)(x >> 32), m);
  return ((u64)(unsigned)hi << 32) | (u64)(unsigned)lo;
}

// ---------------- Kernel 1: DTM (unchanged) ----------------
__global__ __launch_bounds__(1024) void dtm_kernel(const float* __restrict__ win,
                                                   float* __restrict__ fout) {
  __shared__ float P0[64][65];
  __shared__ float P1[64][65];
  __shared__ float P2[64][65];
  int b = blockIdx.y;
  const float* w = win + b * NPTS;
  int tid = threadIdx.x, lane = tid & 63, wv = tid >> 6;

  for (int rr = 0; rr < 4; ++rr) {
    int r = (wv << 2) | rr;
    float x0 = w[(r << 6) | lane];
    float fl = (float)lane;
    float x1 = x0 * fl, x2 = x1 * fl;
    for (int d = 1; d < 64; d <<= 1) {
      float t0 = __shfl_up(x0, d);
      float t1 = __shfl_up(x1, d);
      float t2 = __shfl_up(x2, d);
      if (lane >= d) { x0 += t0; x1 += t1; x2 += t2; }
    }
    P0[r][lane] = x0; P1[r][lane] = x1; P2[r][lane] = x2;
  }
  __syncthreads();

  float sumw = waveSum(P0[lane][63]);
  float thr = M0f * sumw;

  int q = blockIdx.x * 16 + wv;
  int qi = q >> 6, qj = q & 63;
  int di = qi - lane;
  int disq = di * di;

  auto evalF = [&](int K) -> float {
    float s0 = 0.f;
    int rem = K - disq;
    if (rem >= 0) {
      int r = isqrt_i(rem);
      int l0 = qj - r; l0 = l0 < 0 ? 0 : l0;
      int h0 = qj + r; h0 = h0 > 63 ? 63 : h0;
      s0 = P0[lane][h0] - (l0 > 0 ? P0[lane][l0 - 1] : 0.f);
    }
    return waveSum(s0);
  };

  int lo = -1, hi = 256;
  float Flo = 0.f;
  for (;;) {
    float F = evalF(hi);
    if (F >= thr || hi == KMAXD2) break;
    lo = hi; Flo = F;
    hi = (hi == 256) ? 1024 : KMAXD2;
  }
  while (hi - lo > 1) {
    int mid = (lo + hi) >> 1;
    float F = evalF(mid);
    if (F >= thr) hi = mid; else { lo = mid; Flo = F; }
  }
  int kstar = hi;
  float Fm = Flo;

  float g = 0.f;
  {
    int rem = (kstar - 1) - disq;
    if (rem >= 0) {
      int r = isqrt_i(rem);
      int l0 = qj - r; l0 = l0 < 0 ? 0 : l0;
      int h0 = qj + r; h0 = h0 > 63 ? 63 : h0;
      float S0 = P0[lane][h0] - (l0 > 0 ? P0[lane][l0 - 1] : 0.f);
      float S1 = P1[lane][h0] - (l0 > 0 ? P1[lane][l0 - 1] : 0.f);
      float S2 = P2[lane][h0] - (l0 > 0 ? P2[lane][l0 - 1] : 0.f);
      float fq = (float)qj;
      g = (float)disq * S0 + fq * fq * S0 - 2.f * fq * S1 + S2;
    }
  }
  float G = waveSum(g);
  float val = (G + (thr - Fm) * (float)kstar) / thr;
  val = val < 0.f ? 0.f : val;
  float res = (224.f / 63.f) * sqrtf(val);
  if (lane == 0) fout[b * NPTS + q] = res;
}

// ---------------- Kernel A: basins (descent + jump + compact) ----------------
__global__ __launch_bounds__(1024) void basin_kernel(const float* __restrict__ fin,
                                                     int* __restrict__ bas_out,
                                                     float* __restrict__ mu_out,
                                                     int* __restrict__ mv_out,
                                                     unsigned* __restrict__ mm_out) {
  __shared__ float sf[NPTS];
  __shared__ int srep[NPTS];
  __shared__ int sbasin[NPTS];
  __shared__ float smu[128];
  __shared__ int sminv[128];
  __shared__ int c_m;
  __shared__ unsigned fminb, fmaxb;

  int b = blockIdx.x;
  int tid = threadIdx.x;
  if (tid == 0) { c_m = 0; fminb = 0x7f800000u; fmaxb = 0u; }
  if (tid < 128) { smu[tid] = 3.0e38f; sminv[tid] = tid; }

  {
    float lmin = 3.0e38f, lmax = 0.f;
    for (int v = tid; v < NPTS; v += 1024) {
      float x = fin[b * NPTS + v];
      sf[v] = x;
      lmin = fminf(lmin, x);
      lmax = fmaxf(lmax, x);
    }
    for (int m = 32; m >= 1; m >>= 1) {
      lmin = fminf(lmin, __shfl_xor(lmin, m));
      lmax = fmaxf(lmax, __shfl_xor(lmax, m));
    }
    if ((tid & 63) == 0) {
      atomicMin(&fminb, __float_as_uint(lmin));
      atomicMax(&fmaxb, __float_as_uint(lmax));
    }
  }
  __syncthreads();

  int preg[4];
#pragma unroll 4
  for (int s = 0; s < 4; ++s) {
    int v = tid + s * 1024;
    int vi = v >> 6, vj = v & 63;
    float bf = sf[v]; int bi = v;
    if (vj > 0)  { float fn = sf[v - 1];  int n = v - 1;  if (fn < bf || (fn == bf && n < bi)) { bf = fn; bi = n; } }
    if (vj < 63) { float fn = sf[v + 1];  int n = v + 1;  if (fn < bf || (fn == bf && n < bi)) { bf = fn; bi = n; } }
    if (vi > 0)  { float fn = sf[v - 64]; int n = v - 64; if (fn < bf || (fn == bf && n < bi)) { bf = fn; bi = n; } }
    if (vi < 63) { float fn = sf[v + 64]; int n = v + 64; if (fn < bf || (fn == bf && n < bi)) { bf = fn; bi = n; } }
    srep[v] = bi;
    preg[s] = bi;
  }
  __syncthreads();

  for (int it = 0; it < 12; ++it) {
#pragma unroll 4
    for (int s = 0; s < 4; ++s) {
      int x = srep[preg[s]];
      srep[tid + s * 1024] = x;
      preg[s] = x;
    }
    __syncthreads();
  }

  for (int v = tid; v < NPTS; v += 1024) {
    if (srep[v] == v) {
      int id = atomicAdd(&c_m, 1);
      if (id < IDCAP) { sbasin[v] = id; smu[id] = sf[v]; sminv[id] = v; }
      else sbasin[v] = IDCAP - 1;
    }
  }
  __syncthreads();
  for (int v = tid; v < NPTS; v += 1024) {
    if (srep[v] != v) sbasin[v] = sbasin[srep[v]];
  }
  __syncthreads();

  for (int v = tid; v < NPTS; v += 1024) bas_out[b * NPTS + v] = sbasin[v];
  if (tid < 128) { mu_out[b * 128 + tid] = smu[tid]; mv_out[b * 128 + tid] = sminv[tid]; }
  if (tid == 0) { mm_out[b * 2] = fminb; mm_out[b * 2 + 1] = fmaxb; }
}

// ---- in-wave bitonic compare-exchange macros (512 elems, 8 u64/lane) ----
#define CXL(R, J, K) { \
  u64 vo = shfl_xor64(e##R, J); \
  bool up = (((((R) * 64) & (K)) | (lane & (K))) == 0); \
  bool lower = ((lane & (J)) == 0); \
  bool kmin = (lower == up); \
  u64 mn = (e##R < vo) ? e##R : vo; \
  u64 mx = (e##R < vo) ? vo : e##R; \
  e##R = kmin ? mn : mx; }
#define ALL8(J, K) CXL(0,J,K) CXL(1,J,K) CXL(2,J,K) CXL(3,J,K) CXL(4,J,K) CXL(5,J,K) CXL(6,J,K) CXL(7,J,K)
#define CXR(RA, RB, K) { \
  const bool up = ((((RA) * 64) & (K)) == 0); \
  u64 va = e##RA, vb = e##RB; \
  u64 mn = (va < vb) ? va : vb; \
  u64 mx = (va < vb) ? vb : va; \
  e##RA = up ? mn : mx; e##RB = up ? mx : mn; }

// ---------------- Kernel B: edges + dedup + sort + Kruskal ----------------
__global__ __launch_bounds__(1024) void mst_kernel(const float* __restrict__ fin,
                                                   const int* __restrict__ bas_in,
                                                   const float* __restrict__ mu_in,
                                                   const int* __restrict__ mv_in,
                                                   const unsigned* __restrict__ mm_in,
                                                   int* __restrict__ np_out,
                                                   float2* __restrict__ pairs_out) {
  __shared__ float sf[NPTS];
  __shared__ int sbin[NPTS];
  __shared__ unsigned ptable[4096];
  __shared__ __align__(16) u64 slist2[SORTCAP];
  __shared__ float2 spairs[PAIRCAP];
  __shared__ int c_l2, c_np;

  int b = blockIdx.x;
  int tid = threadIdx.x;
  if (tid == 0) { c_l2 = 0; c_np = 0; }
  for (int v = tid; v < NPTS; v += 1024) {
    sf[v] = fin[b * NPTS + v];
    sbin[v] = bas_in[b * NPTS + v];
    ptable[v] = 0xFFFFFFFFu;
  }
  __syncthreads();

  for (int e = tid; e < NEDGE; e += 1024) {
    int u, v2;
    if (e < 4032) { int i = e / 63; int j = e - i * 63; u = (i << 6) | j; v2 = u + 1; }
    else          { int e2 = e - 4032; u = e2; v2 = u + 64; }
    int bu = sbin[u], bv = sbin[v2];
    if (bu != bv) {
      float wgt = fmaxf(sf[u], sf[v2]);
      int a = bu < bv ? bu : bv, bb2 = bu < bv ? bv : bu;
      int t = (bb2 * (bb2 - 1)) / 2 + a;
      atomicMin(&ptable[t], __float_as_uint(wgt));
    }
  }
  __syncthreads();

  for (int t = tid; t < 4096; t += 1024) {
    unsigned wv2 = ptable[t];
    if (wv2 != 0xFFFFFFFFu) {
      int bb2 = (int)((1.0f + sqrtf(1.0f + 8.0f * (float)t)) * 0.5f);
      while (bb2 > 1 && (bb2 * (bb2 - 1)) / 2 > t) bb2--;
      while (((bb2 + 1) * bb2) / 2 <= t) bb2++;
      int aa = t - (bb2 * (bb2 - 1)) / 2;
      int slot = atomicAdd(&c_l2, 1);
      if (slot < SORTCAP) slist2[slot] = ((u64)wv2 << 32) | (unsigned)((bb2 << 8) | aa);
    }
  }
  __syncthreads();
  int n2 = c_l2; if (n2 > SORTCAP) n2 = SORTCAP;
  for (int i = n2 + tid; i < SORTCAP; i += 1024) slist2[i] = ~0ull;
  __syncthreads();

  int lane = tid & 63;
  if (tid < 64) {
    u64 e0 = slist2[lane],        e1 = slist2[64 + lane],  e2 = slist2[128 + lane], e3 = slist2[192 + lane];
    u64 e4 = slist2[256 + lane],  e5 = slist2[320 + lane], e6 = slist2[384 + lane], e7 = slist2[448 + lane];
    ALL8(1,2)
    ALL8(2,4) ALL8(1,4)
    ALL8(4,8) ALL8(2,8) ALL8(1,8)
    ALL8(8,16) ALL8(4,16) ALL8(2,16) ALL8(1,16)
    ALL8(16,32) ALL8(8,32) ALL8(4,32) ALL8(2,32) ALL8(1,32)
    ALL8(32,64) ALL8(16,64) ALL8(8,64) ALL8(4,64) ALL8(2,64) ALL8(1,64)
    CXR(0,1,128) CXR(2,3,128) CXR(4,5,128) CXR(6,7,128)
    ALL8(32,128) ALL8(16,128) ALL8(8,128) ALL8(4,128) ALL8(2,128) ALL8(1,128)
    CXR(0,2,256) CXR(1,3,256) CXR(4,6,256) CXR(5,7,256)
    CXR(0,1,256) CXR(2,3,256) CXR(4,5,256) CXR(6,7,256)
    ALL8(32,256) ALL8(16,256) ALL8(8,256) ALL8(4,256) ALL8(2,256) ALL8(1,256)
    CXR(0,4,512) CXR(1,5,512) CXR(2,6,512) CXR(3,7,512)
    CXR(0,2,512) CXR(1,3,512) CXR(4,6,512) CXR(5,7,512)
    CXR(0,1,512) CXR(2,3,512) CXR(4,5,512) CXR(6,7,512)
    ALL8(32,512) ALL8(16,512) ALL8(8,512) ALL8(4,512) ALL8(2,512) ALL8(1,512)

    // Kruskal; lane carries for ids (lane) and (64+lane): current ROOT p, root's mu m, root's min-vertex r.
    int p0 = lane, p1 = 64 + lane;
    float m0 = mu_in[b * 128 + lane], m1 = mu_in[b * 128 + 64 + lane];
    int r0 = mv_in[b * 128 + lane], r1 = mv_in[b * 128 + 64 + lane];
    int np = 0;
#define KBATCH(R) { \
      u64 ev = e##R; \
      bool valid = (ev != ~0ull); \
      int a_l = (int)(ev & 0xffull); \
      int b_l = (int)((ev >> 8) & 0xffull); \
      int ra_pre = (a_l < 64) ? __shfl(p0, a_l) : __shfl(p1, a_l & 63); \
      int rb_pre = (b_l < 64) ? __shfl(p0, b_l) : __shfl(p1, b_l & 63); \
      u64 cand = __ballot(valid && (ra_pre != rb_pre)); \
      while (cand) { \
        int s = __builtin_ctzll(cand); cand &= cand - 1; \
        int a = __shfl(a_l, s), bb2 = __shfl(b_l, s); \
        int pa = (a < 64) ? __shfl(p0, a) : __shfl(p1, a & 63); \
        int pb = (bb2 < 64) ? __shfl(p0, bb2) : __shfl(p1, bb2 & 63); \
        float ma = (a < 64) ? __shfl(m0, a) : __shfl(m1, a & 63); \
        float mb = (bb2 < 64) ? __shfl(m0, bb2) : __shfl(m1, bb2 & 63); \
        int ra = (a < 64) ? __shfl(r0, a) : __shfl(r1, a & 63); \
        int rb = (bb2 < 64) ? __shfl(r0, bb2) : __shfl(r1, bb2 & 63); \
        if (pa == pb) continue; \
        bool aeld = (ma < mb) || (ma == mb && ra <= rb); \
        int eld = aeld ? pa : pb, yng = aeld ? pb : pa; \
        float m_e = aeld ? ma : mb; int r_e = aeld ? ra : rb; \
        float byoung = aeld ? mb : ma; \
        bool h0 = (p0 == yng), h1 = (p1 == yng); \
        p0 = h0 ? eld : p0; m0 = h0 ? m_e : m0; r0 = h0 ? r_e : r0; \
        p1 = h1 ? eld : p1; m1 = h1 ? m_e : m1; r1 = h1 ? r_e : r1; \
        if (lane == s && np < PAIRCAP - 1) spairs[np] = make_float2(byoung, __uint_as_float((unsigned)(ev >> 32))); \
        np++; \
      } }
    KBATCH(0) KBATCH(1) KBATCH(2) KBATCH(3) KBATCH(4) KBATCH(5) KBATCH(6) KBATCH(7)
#undef KBATCH
    if (np > PAIRCAP - 1) np = PAIRCAP - 1;
    if (lane == 0) {
      spairs[np] = make_float2(__uint_as_float(mm_in[b * 2]), __uint_as_float(mm_in[b * 2 + 1]));
      c_np = np + 1;
    }
  }
  __syncthreads();
  int totp = c_np;
  if (tid == 0) np_out[b] = totp;
  for (int i = tid; i < totp; i += 1024) pairs_out[b * PAIRCAP + i] = spairs[i];
}

// ---------------- Kernel C: landscape + MLP (both batches, 1 block) ----------------
__global__ __launch_bounds__(512) void land_mlp_kernel(const int* __restrict__ np_in,
                                                       const float2* __restrict__ pairs_in,
                                                       const float* __restrict__ Wg,
                                                       const float* __restrict__ bg,
                                                       const float* __restrict__ Wfc,
                                                       const float* __restrict__ bfc,
                                                       float* __restrict__ out) {
  __shared__ float2 sp[2][PAIRCAP];
  __shared__ int snp[2];
  __shared__ float sland[2][50];
  __shared__ float sx[2][50];
  __shared__ float sWg[2500];
  __shared__ float sbg[50];
  __shared__ float sWfc[500];
  __shared__ float sbfc[10];
  int tid = threadIdx.x;
  if (tid < 2) snp[tid] = np_in[tid];
  for (int i = tid; i < 2 * PAIRCAP; i += 512) sp[i / PAIRCAP][i % PAIRCAP] = pairs_in[i];
  for (int i = tid; i < 2500; i += 512) sWg[i] = Wg[i];
  for (int i = tid; i < 500; i += 512) sWfc[i] = Wfc[i];
  if (tid < 50) sbg[tid] = bg[tid];
  if (tid < 10) sbfc[tid] = bfc[tid];
  __syncthreads();

  if (tid < 50) {
    int b = tid / 25, t = tid % 25;
    float tv = 1.875f * (float)t;
    float top1 = 0.f, top2 = 0.f;
    int n = snp[b];
    for (int i = 0; i < n; ++i) {
      float2 p = sp[b][i];
      float tri = fminf(tv - p.x, p.y - tv);
      tri = fmaxf(tri, 0.f);
      if (tri > top1) { top2 = top1; top1 = tri; }
      else if (tri > top2) top2 = tri;
    }
    sland[b][t] = top1;
    sland[b][25 + t] = top2;
  }
  __syncthreads();
  if (tid < 100) {
    int b = tid / 50, o = tid % 50;
    float acc = sbg[o];
    for (int k = 0; k < 50; ++k) acc += sland[b][k] * sWg[o * 50 + k];
    sx[b][o] = acc;
  }
  __syncthreads();
  if (tid < 50) out[20 + tid] = fabsf(sx[0][tid]) + fabsf(sx[1][tid]);
  if (tid >= 128 && tid < 148) {
    int t2 = tid - 128;
    int b = t2 / 10, c = t2 % 10;
    float acc = sbfc[c];
    for (int o = 0; o < 50; ++o) acc += fmaxf(sx[b][o], 0.f) * sWfc[c * 50 + o];
    out[b * 10 + c] = acc;
  }
}

extern "C" void kernel_launch(void* const* d_in, const int* in_sizes, int n_in,
                              void* d_out, int out_size, void* d_ws, size_t ws_size,
                              hipStream_t stream) {
  (void)in_sizes; (void)n_in; (void)out_size; (void)ws_size;
  const float* input = (const float*)d_in[0];
  const float* Wg  = (const float*)d_in[1];
  const float* bg  = (const float*)d_in[2];
  const float* Wfc = (const float*)d_in[3];
  const float* bfc = (const float*)d_in[4];
  float* out = (float*)d_out;

  char* ws = (char*)d_ws;
  float*    f_ws    = (float*)(ws + F_OFF);
  int*      bas_ws  = (int*)(ws + BAS_OFF);
  float*    mu_ws   = (float*)(ws + MU_OFF);
  int*      mv_ws   = (int*)(ws + MV_OFF);
  unsigned* mm_ws   = (unsigned*)(ws + MM_OFF);
  int*      np_ws   = (int*)(ws + NP_OFF);
  float2*   pr_ws   = (float2*)(ws + PR_OFF);

  dtm_kernel<<<dim3(256, 2), 1024, 0, stream>>>(input, f_ws);
  basin_kernel<<<dim3(2), 1024, 0, stream>>>(f_ws, bas_ws, mu_ws, mv_ws, mm_ws);
  mst_kernel<<<dim3(2), 1024, 0, stream>>>(f_ws, bas_ws, mu_ws, mv_ws, mm_ws, np_ws, pr_ws);
  land_mlp_kernel<<<1, 512, 0, stream>>>(np_ws, pr_ws, Wg, bg, Wfc, bfc, out);
}

// Round 11
// 79.116 us; speedup vs baseline: 1.1340x; 1.1340x over previous
//
#include <hip/hip_runtime.h>

#define NPTS 4096
#define NEDGE 8064
#define M0f 0.05f
#define KMAXD2 7938
#define IDCAP 90          // basin-id clamp; triangular pair table needs IDCAP*(IDCAP-1)/2 <= 4096
#define SORTCAP 512
#define PAIRCAP 160

// ---- ws byte offsets ----
#define F_OFF   0         // float[2][4096]
#define BAS_OFF 32768     // int[2][4096]
#define MU_OFF  65536     // float[2][128]
#define MV_OFF  66560     // int[2][128]
#define MM_OFF  67584     // uint[2][2]  (min,max bits)
#define NP_OFF  67600     // int[2]
#define PR_OFF  67616     // float2[2][PAIRCAP]

typedef unsigned long long u64;

__device__ inline float waveSum(float x) {
  for (int m = 32; m >= 1; m >>= 1) x += __shfl_xor(x, m);
  return x;
}

__device__ inline int isqrt_i(int x) {  // exact floor sqrt for 0 <= x < 2^20
  int r = (int)sqrtf((float)x);
  if ((r + 1) * (r + 1) <= x) r++;
  else if (r * r > x) r--;
  return r;
}

// uniform-index readlane helpers (VALU->SGPR, no LDS; index must be wave-uniform)
__device__ inline int rdl(int v, int l) { return __builtin_amdgcn_readlane(v, l); }
__device__ inline float rdlf(float v, int l) {
  return __uint_as_float((unsigned)__builtin_amdgcn_readlane((int)__float_as_uint(v), l));
}

// ---------------- Kernel 1: DTM (unchanged) ----------------
__global__ __launch_bounds__(1024) void dtm_kernel(const float* __restrict__ win,
                                                   float* __restrict__ fout) {
  __shared__ float P0[64][65];
  __shared__ float P1[64][65];
  __shared__ float P2[64][65];
  int b = blockIdx.y;
  const float* w = win + b * NPTS;
  int tid = threadIdx.x, lane = tid & 63, wv = tid >> 6;

  for (int rr = 0; rr < 4; ++rr) {
    int r = (wv << 2) | rr;
    float x0 = w[(r << 6) | lane];
    float fl = (float)lane;
    float x1 = x0 * fl, x2 = x1 * fl;
    for (int d = 1; d < 64; d <<= 1) {
      float t0 = __shfl_up(x0, d);
      float t1 = __shfl_up(x1, d);
      float t2 = __shfl_up(x2, d);
      if (lane >= d) { x0 += t0; x1 += t1; x2 += t2; }
    }
    P0[r][lane] = x0; P1[r][lane] = x1; P2[r][lane] = x2;
  }
  __syncthreads();

  float sumw = waveSum(P0[lane][63]);
  float thr = M0f * sumw;

  int q = blockIdx.x * 16 + wv;
  int qi = q >> 6, qj = q & 63;
  int di = qi - lane;
  int disq = di * di;

  auto evalF = [&](int K) -> float {
    float s0 = 0.f;
    int rem = K - disq;
    if (rem >= 0) {
      int r = isqrt_i(rem);
      int l0 = qj - r; l0 = l0 < 0 ? 0 : l0;
      int h0 = qj + r; h0 = h0 > 63 ? 63 : h0;
      s0 = P0[lane][h0] - (l0 > 0 ? P0[lane][l0 - 1] : 0.f);
    }
    return waveSum(s0);
  };

  int lo = -1, hi = 256;
  float Flo = 0.f;
  for (;;) {
    float F = evalF(hi);
    if (F >= thr || hi == KMAXD2) break;
    lo = hi; Flo = F;
    hi = (hi == 256) ? 1024 : KMAXD2;
  }
  while (hi - lo > 1) {
    int mid = (lo + hi) >> 1;
    float F = evalF(mid);
    if (F >= thr) hi = mid; else { lo = mid; Flo = F; }
  }
  int kstar = hi;
  float Fm = Flo;

  float g = 0.f;
  {
    int rem = (kstar - 1) - disq;
    if (rem >= 0) {
      int r = isqrt_i(rem);
      int l0 = qj - r; l0 = l0 < 0 ? 0 : l0;
      int h0 = qj + r; h0 = h0 > 63 ? 63 : h0;
      float S0 = P0[lane][h0] - (l0 > 0 ? P0[lane][l0 - 1] : 0.f);
      float S1 = P1[lane][h0] - (l0 > 0 ? P1[lane][l0 - 1] : 0.f);
      float S2 = P2[lane][h0] - (l0 > 0 ? P2[lane][l0 - 1] : 0.f);
      float fq = (float)qj;
      g = (float)disq * S0 + fq * fq * S0 - 2.f * fq * S1 + S2;
    }
  }
  float G = waveSum(g);
  float val = (G + (thr - Fm) * (float)kstar) / thr;
  val = val < 0.f ? 0.f : val;
  float res = (224.f / 63.f) * sqrtf(val);
  if (lane == 0) fout[b * NPTS + q] = res;
}

// ---------------- Kernel A: basins (descent + jump + compact) ----------------
__global__ __launch_bounds__(1024) void basin_kernel(const float* __restrict__ fin,
                                                     int* __restrict__ bas_out,
                                                     float* __restrict__ mu_out,
                                                     int* __restrict__ mv_out,
                                                     unsigned* __restrict__ mm_out) {
  __shared__ float sf[NPTS];
  __shared__ int srep[NPTS];
  __shared__ int sbasin[NPTS];
  __shared__ float smu[128];
  __shared__ int sminv[128];
  __shared__ int c_m;
  __shared__ unsigned fminb, fmaxb;

  int b = blockIdx.x;
  int tid = threadIdx.x;
  if (tid == 0) { c_m = 0; fminb = 0x7f800000u; fmaxb = 0u; }
  if (tid < 128) { smu[tid] = 3.0e38f; sminv[tid] = tid; }

  {
    float lmin = 3.0e38f, lmax = 0.f;
    for (int v = tid; v < NPTS; v += 1024) {
      float x = fin[b * NPTS + v];
      sf[v] = x;
      lmin = fminf(lmin, x);
      lmax = fmaxf(lmax, x);
    }
    for (int m = 32; m >= 1; m >>= 1) {
      lmin = fminf(lmin, __shfl_xor(lmin, m));
      lmax = fmaxf(lmax, __shfl_xor(lmax, m));
    }
    if ((tid & 63) == 0) {
      atomicMin(&fminb, __float_as_uint(lmin));
      atomicMax(&fmaxb, __float_as_uint(lmax));
    }
  }
  __syncthreads();

  int preg[4];
#pragma unroll 4
  for (int s = 0; s < 4; ++s) {
    int v = tid + s * 1024;
    int vi = v >> 6, vj = v & 63;
    float bf = sf[v]; int bi = v;
    if (vj > 0)  { float fn = sf[v - 1];  int n = v - 1;  if (fn < bf || (fn == bf && n < bi)) { bf = fn; bi = n; } }
    if (vj < 63) { float fn = sf[v + 1];  int n = v + 1;  if (fn < bf || (fn == bf && n < bi)) { bf = fn; bi = n; } }
    if (vi > 0)  { float fn = sf[v - 64]; int n = v - 64; if (fn < bf || (fn == bf && n < bi)) { bf = fn; bi = n; } }
    if (vi < 63) { float fn = sf[v + 64]; int n = v + 64; if (fn < bf || (fn == bf && n < bi)) { bf = fn; bi = n; } }
    srep[v] = bi;
    preg[s] = bi;
  }
  __syncthreads();

  for (int it = 0; it < 12; ++it) {
#pragma unroll 4
    for (int s = 0; s < 4; ++s) {
      int x = srep[preg[s]];
      srep[tid + s * 1024] = x;
      preg[s] = x;
    }
    __syncthreads();
  }

  for (int v = tid; v < NPTS; v += 1024) {
    if (srep[v] == v) {
      int id = atomicAdd(&c_m, 1);
      if (id < IDCAP) { sbasin[v] = id; smu[id] = sf[v]; sminv[id] = v; }
      else sbasin[v] = IDCAP - 1;
    }
  }
  __syncthreads();
  for (int v = tid; v < NPTS; v += 1024) {
    if (srep[v] != v) sbasin[v] = sbasin[srep[v]];
  }
  __syncthreads();

  for (int v = tid; v < NPTS; v += 1024) bas_out[b * NPTS + v] = sbasin[v];
  if (tid < 128) { mu_out[b * 128 + tid] = smu[tid]; mv_out[b * 128 + tid] = sminv[tid]; }
  if (tid == 0) { mm_out[b * 2] = fminb; mm_out[b * 2 + 1] = fmaxb; }
}

// ---------------- Kernel B: edges + dedup + LDS sort + readlane Kruskal ----------------
__global__ __launch_bounds__(1024) void mst_kernel(const float* __restrict__ fin,
                                                   const int* __restrict__ bas_in,
                                                   const float* __restrict__ mu_in,
                                                   const int* __restrict__ mv_in,
                                                   const unsigned* __restrict__ mm_in,
                                                   int* __restrict__ np_out,
                                                   float2* __restrict__ pairs_out) {
  __shared__ float sf[NPTS];
  __shared__ int sbin[NPTS];
  __shared__ unsigned ptable[4096];
  __shared__ __align__(16) u64 slist2[SORTCAP];
  __shared__ float2 spairs[PAIRCAP];
  __shared__ int c_l2, c_np;

  int b = blockIdx.x;
  int tid = threadIdx.x;
  if (tid == 0) { c_l2 = 0; c_np = 0; }
  for (int v = tid; v < NPTS; v += 1024) {
    sf[v] = fin[b * NPTS + v];
    sbin[v] = bas_in[b * NPTS + v];
    ptable[v] = 0xFFFFFFFFu;
  }
  __syncthreads();

  for (int e = tid; e < NEDGE; e += 1024) {
    int u, v2;
    if (e < 4032) { int i = e / 63; int j = e - i * 63; u = (i << 6) | j; v2 = u + 1; }
    else          { int e2 = e - 4032; u = e2; v2 = u + 64; }
    int bu = sbin[u], bv = sbin[v2];
    if (bu != bv) {
      float wgt = fmaxf(sf[u], sf[v2]);
      int a = bu < bv ? bu : bv, bb2 = bu < bv ? bv : bu;
      int t = (bb2 * (bb2 - 1)) / 2 + a;
      atomicMin(&ptable[t], __float_as_uint(wgt));
    }
  }
  __syncthreads();

  for (int t = tid; t < 4096; t += 1024) {
    unsigned wv2 = ptable[t];
    if (wv2 != 0xFFFFFFFFu) {
      int bb2 = (int)((1.0f + sqrtf(1.0f + 8.0f * (float)t)) * 0.5f);
      while (bb2 > 1 && (bb2 * (bb2 - 1)) / 2 > t) bb2--;
      while (((bb2 + 1) * bb2) / 2 <= t) bb2++;
      int aa = t - (bb2 * (bb2 - 1)) / 2;
      int slot = atomicAdd(&c_l2, 1);
      if (slot < SORTCAP) slist2[slot] = ((u64)wv2 << 32) | (unsigned)((bb2 << 8) | aa);
    }
  }
  __syncthreads();
  int n2 = c_l2; if (n2 > SORTCAP) n2 = SORTCAP;
  int npad2 = 1; while (npad2 < n2) npad2 <<= 1;
  if (n2 == 0) npad2 = 0;
  for (int i = n2 + tid; i < npad2; i += 1024) slist2[i] = ~0ull;
  __syncthreads();

  // LDS bitonic over npad2 (all threads; ~36 barriered passes at npad2=256)
  for (int k = 2; k <= npad2; k <<= 1) {
    for (int j = k >> 1; j > 0; j >>= 1) {
      for (int i = tid; i < npad2; i += 1024) {
        int ixj = i ^ j;
        if (ixj > i) {
          u64 x = slist2[i], y = slist2[ixj];
          bool up = ((i & k) == 0);
          if (up ? (x > y) : (x < y)) { slist2[i] = y; slist2[ixj] = x; }
        }
      }
      __syncthreads();
    }
  }

  // wave 0: serial Kruskal; all dynamic accesses via uniform readlane (no bpermute chain)
  int lane = tid & 63;
  if (tid < 64) {
    // lane carries, for ids (lane) and (64+lane): current ROOT p, root's mu m, root's min-vertex r
    int p0 = lane, p1 = 64 + lane;
    float m0 = mu_in[b * 128 + lane], m1 = mu_in[b * 128 + 64 + lane];
    int r0 = mv_in[b * 128 + lane], r1 = mv_in[b * 128 + 64 + lane];
    int np = 0;
    for (int base = 0; base < n2; base += 64) {
      int idx = base + lane;
      u64 ev = (idx < n2) ? slist2[idx] : ~0ull;
      int a_l = (int)(ev & 0xffull);
      int b_l = (int)((ev >> 8) & 0xffull);
      int w_l = (int)(unsigned)(ev >> 32);
      // per-lane prefilter (vector shfl ok here; throughput, not chain)
      int ra_pre = (a_l < 64) ? __shfl(p0, a_l) : __shfl(p1, a_l & 63);
      int rb_pre = (b_l < 64) ? __shfl(p0, b_l) : __shfl(p1, b_l & 63);
      u64 cand = __ballot((idx < n2) && (ra_pre != rb_pre));
      while (cand) {
        int s = __builtin_ctzll(cand); cand &= cand - 1;
        int a   = rdl(a_l, s);
        int bb2 = rdl(b_l, s);
        int wb  = rdl(w_l, s);
        int ia = a & 63, ib = bb2 & 63;
        int pa = (a < 64)   ? rdl(p0, ia) : rdl(p1, ia);
        int pb = (bb2 < 64) ? rdl(p0, ib) : rdl(p1, ib);
        if (pa == pb) continue;
        float ma = (a < 64)   ? rdlf(m0, ia) : rdlf(m1, ia);
        float mb = (bb2 < 64) ? rdlf(m0, ib) : rdlf(m1, ib);
        int ra = (a < 64)   ? rdl(r0, ia) : rdl(r1, ia);
        int rb = (bb2 < 64) ? rdl(r0, ib) : rdl(r1, ib);
        bool aeld = (ma < mb) || (ma == mb && ra <= rb);
        int eld = aeld ? pa : pb, yng = aeld ? pb : pa;
        float m_e = aeld ? ma : mb; int r_e = aeld ? ra : rb;
        float byoung = aeld ? mb : ma;
        bool h0 = (p0 == yng), h1 = (p1 == yng);
        p0 = h0 ? eld : p0; m0 = h0 ? m_e : m0; r0 = h0 ? r_e : r0;
        p1 = h1 ? eld : p1; m1 = h1 ? m_e : m1; r1 = h1 ? r_e : r1;
        if (lane == 0 && np < PAIRCAP - 1) spairs[np] = make_float2(byoung, __uint_as_float((unsigned)wb));
        np++;
      }
    }
    if (np > PAIRCAP - 1) np = PAIRCAP - 1;
    if (lane == 0) {
      spairs[np] = make_float2(__uint_as_float(mm_in[b * 2]), __uint_as_float(mm_in[b * 2 + 1]));
      c_np = np + 1;
    }
  }
  __syncthreads();
  int totp = c_np;
  if (tid == 0) np_out[b] = totp;
  for (int i = tid; i < totp; i += 1024) pairs_out[b * PAIRCAP + i] = spairs[i];
}

// ---------------- Kernel C: landscape + MLP (both batches, 1 block) ----------------
__global__ __launch_bounds__(512) void land_mlp_kernel(const int* __restrict__ np_in,
                                                       const float2* __restrict__ pairs_in,
                                                       const float* __restrict__ Wg,
                                                       const float* __restrict__ bg,
                                                       const float* __restrict__ Wfc,
                                                       const float* __restrict__ bfc,
                                                       float* __restrict__ out) {
  __shared__ float2 sp[2][PAIRCAP];
  __shared__ int snp[2];
  __shared__ float sland[2][50];
  __shared__ float sx[2][50];
  __shared__ float sWg[2500];
  __shared__ float sbg[50];
  __shared__ float sWfc[500];
  __shared__ float sbfc[10];
  int tid = threadIdx.x;
  if (tid < 2) snp[tid] = np_in[tid];
  for (int i = tid; i < 2 * PAIRCAP; i += 512) sp[i / PAIRCAP][i % PAIRCAP] = pairs_in[i];
  for (int i = tid; i < 2500; i += 512) sWg[i] = Wg[i];
  for (int i = tid; i < 500; i += 512) sWfc[i] = Wfc[i];
  if (tid < 50) sbg[tid] = bg[tid];
  if (tid < 10) sbfc[tid] = bfc[tid];
  __syncthreads();

  if (tid < 50) {
    int b = tid / 25, t = tid % 25;
    float tv = 1.875f * (float)t;
    float top1 = 0.f, top2 = 0.f;
    int n = snp[b];
    for (int i = 0; i < n; ++i) {
      float2 p = sp[b][i];
      float tri = fminf(tv - p.x, p.y - tv);
      tri = fmaxf(tri, 0.f);
      if (tri > top1) { top2 = top1; top1 = tri; }
      else if (tri > top2) top2 = tri;
    }
    sland[b][t] = top1;
    sland[b][25 + t] = top2;
  }
  __syncthreads();
  if (tid < 100) {
    int b = tid / 50, o = tid % 50;
    float acc = sbg[o];
    for (int k = 0; k < 50; ++k) acc += sland[b][k] * sWg[o * 50 + k];
    sx[b][o] = acc;
  }
  __syncthreads();
  if (tid < 50) out[20 + tid] = fabsf(sx[0][tid]) + fabsf(sx[1][tid]);
  if (tid >= 128 && tid < 148) {
    int t2 = tid - 128;
    int b = t2 / 10, c = t2 % 10;
    float acc = sbfc[c];
    for (int o = 0; o < 50; ++o) acc += fmaxf(sx[b][o], 0.f) * sWfc[c * 50 + o];
    out[b * 10 + c] = acc;
  }
}

extern "C" void kernel_launch(void* const* d_in, const int* in_sizes, int n_in,
                              void* d_out, int out_size, void* d_ws, size_t ws_size,
                              hipStream_t stream) {
  (void)in_sizes; (void)n_in; (void)out_size; (void)ws_size;
  const float* input = (const float*)d_in[0];
  const float* Wg  = (const float*)d_in[1];
  const float* bg  = (const float*)d_in[2];
  const float* Wfc = (const float*)d_in[3];
  const float* bfc = (const float*)d_in[4];
  float* out = (float*)d_out;

  char* ws = (char*)d_ws;
  float*    f_ws    = (float*)(ws + F_OFF);
  int*      bas_ws  = (int*)(ws + BAS_OFF);
  float*    mu_ws   = (float*)(ws + MU_OFF);
  int*      mv_ws   = (int*)(ws + MV_OFF);
  unsigned* mm_ws   = (unsigned*)(ws + MM_OFF);
  int*      np_ws   = (int*)(ws + NP_OFF);
  float2*   pr_ws   = (float2*)(ws + PR_OFF);

  dtm_kernel<<<dim3(256, 2), 1024, 0, stream>>>(input, f_ws);
  basin_kernel<<<dim3(2), 1024, 0, stream>>>(f_ws, bas_ws, mu_ws, mv_ws, mm_ws);
  mst_kernel<<<dim3(2), 1024, 0, stream>>>(f_ws, bas_ws, mu_ws, mv_ws, mm_ws, np_ws, pr_ws);
  land_mlp_kernel<<<1, 512, 0, stream>>>(np_ws, pr_ws, Wg, bg, Wfc, bfc, out);
}

// Round 12
// 78.526 us; speedup vs baseline: 1.1425x; 1.0075x over previous
//
#include <hip/hip_runtime.h>

#define NPTS 4096
#define NEDGE 8064
#define M0f 0.05f
#define KMAXD2 7938
#define IDCAP 90          // basin-id clamp; triangular pair table needs IDCAP*(IDCAP-1)/2 <= 4096
#define SORTCAP 512
#define PAIRCAP 160

// ---- ws byte offsets ----
#define F_OFF   0         // float[2][4096]
#define BAS_OFF 32768     // int[2][4096]; after mst_sort loads, slist[b] aliases BAS_OFF + b*16384
#define MU_OFF  65536     // float[2][128]
#define MV_OFF  66560     // int[2][128]
#define MM_OFF  67584     // uint[2][2]  (min,max bits)
#define N2_OFF  67600     // int[2]

typedef unsigned long long u64;

__device__ inline float waveSum(float x) {
  for (int m = 32; m >= 1; m >>= 1) x += __shfl_xor(x, m);
  return x;
}

__device__ inline int isqrt_i(int x) {  // exact floor sqrt for 0 <= x < 2^20
  int r = (int)sqrtf((float)x);
  if ((r + 1) * (r + 1) <= x) r++;
  else if (r * r > x) r--;
  return r;
}

// uniform-index readlane helpers (index must be wave-uniform SGPR)
__device__ inline int rdl(int v, int l) { return __builtin_amdgcn_readlane(v, l); }
__device__ inline float rdlf(float v, int l) {
  return __uint_as_float((unsigned)__builtin_amdgcn_readlane((int)__float_as_uint(v), l));
}

// ---------------- Kernel 1: DTM (unchanged) ----------------
__global__ __launch_bounds__(1024) void dtm_kernel(const float* __restrict__ win,
                                                   float* __restrict__ fout) {
  __shared__ float P0[64][65];
  __shared__ float P1[64][65];
  __shared__ float P2[64][65];
  int b = blockIdx.y;
  const float* w = win + b * NPTS;
  int tid = threadIdx.x, lane = tid & 63, wv = tid >> 6;

  for (int rr = 0; rr < 4; ++rr) {
    int r = (wv << 2) | rr;
    float x0 = w[(r << 6) | lane];
    float fl = (float)lane;
    float x1 = x0 * fl, x2 = x1 * fl;
    for (int d = 1; d < 64; d <<= 1) {
      float t0 = __shfl_up(x0, d);
      float t1 = __shfl_up(x1, d);
      float t2 = __shfl_up(x2, d);
      if (lane >= d) { x0 += t0; x1 += t1; x2 += t2; }
    }
    P0[r][lane] = x0; P1[r][lane] = x1; P2[r][lane] = x2;
  }
  __syncthreads();

  float sumw = waveSum(P0[lane][63]);
  float thr = M0f * sumw;

  int q = blockIdx.x * 16 + wv;
  int qi = q >> 6, qj = q & 63;
  int di = qi - lane;
  int disq = di * di;

  auto evalF = [&](int K) -> float {
    float s0 = 0.f;
    int rem = K - disq;
    if (rem >= 0) {
      int r = isqrt_i(rem);
      int l0 = qj - r; l0 = l0 < 0 ? 0 : l0;
      int h0 = qj + r; h0 = h0 > 63 ? 63 : h0;
      s0 = P0[lane][h0] - (l0 > 0 ? P0[lane][l0 - 1] : 0.f);
    }
    return waveSum(s0);
  };

  int lo = -1, hi = 256;
  float Flo = 0.f;
  for (;;) {
    float F = evalF(hi);
    if (F >= thr || hi == KMAXD2) break;
    lo = hi; Flo = F;
    hi = (hi == 256) ? 1024 : KMAXD2;
  }
  while (hi - lo > 1) {
    int mid = (lo + hi) >> 1;
    float F = evalF(mid);
    if (F >= thr) hi = mid; else { lo = mid; Flo = F; }
  }
  int kstar = hi;
  float Fm = Flo;

  float g = 0.f;
  {
    int rem = (kstar - 1) - disq;
    if (rem >= 0) {
      int r = isqrt_i(rem);
      int l0 = qj - r; l0 = l0 < 0 ? 0 : l0;
      int h0 = qj + r; h0 = h0 > 63 ? 63 : h0;
      float S0 = P0[lane][h0] - (l0 > 0 ? P0[lane][l0 - 1] : 0.f);
      float S1 = P1[lane][h0] - (l0 > 0 ? P1[lane][l0 - 1] : 0.f);
      float S2 = P2[lane][h0] - (l0 > 0 ? P2[lane][l0 - 1] : 0.f);
      float fq = (float)qj;
      g = (float)disq * S0 + fq * fq * S0 - 2.f * fq * S1 + S2;
    }
  }
  float G = waveSum(g);
  float val = (G + (thr - Fm) * (float)kstar) / thr;
  val = val < 0.f ? 0.f : val;
  float res = (224.f / 63.f) * sqrtf(val);
  if (lane == 0) fout[b * NPTS + q] = res;
}

// ---------------- Kernel A: basins (descent + jump + compact) ----------------
__global__ __launch_bounds__(1024) void basin_kernel(const float* __restrict__ fin,
                                                     int* __restrict__ bas_out,
                                                     float* __restrict__ mu_out,
                                                     int* __restrict__ mv_out,
                                                     unsigned* __restrict__ mm_out) {
  __shared__ float sf[NPTS];
  __shared__ int srep[NPTS];
  __shared__ int sbasin[NPTS];
  __shared__ float smu[128];
  __shared__ int sminv[128];
  __shared__ int c_m;
  __shared__ unsigned fminb, fmaxb;

  int b = blockIdx.x;
  int tid = threadIdx.x;
  if (tid == 0) { c_m = 0; fminb = 0x7f800000u; fmaxb = 0u; }
  if (tid < 128) { smu[tid] = 3.0e38f; sminv[tid] = tid; }

  {
    float lmin = 3.0e38f, lmax = 0.f;
    for (int v = tid; v < NPTS; v += 1024) {
      float x = fin[b * NPTS + v];
      sf[v] = x;
      lmin = fminf(lmin, x);
      lmax = fmaxf(lmax, x);
    }
    for (int m = 32; m >= 1; m >>= 1) {
      lmin = fminf(lmin, __shfl_xor(lmin, m));
      lmax = fmaxf(lmax, __shfl_xor(lmax, m));
    }
    if ((tid & 63) == 0) {
      atomicMin(&fminb, __float_as_uint(lmin));
      atomicMax(&fmaxb, __float_as_uint(lmax));
    }
  }
  __syncthreads();

  int preg[4];
#pragma unroll 4
  for (int s = 0; s < 4; ++s) {
    int v = tid + s * 1024;
    int vi = v >> 6, vj = v & 63;
    float bf = sf[v]; int bi = v;
    if (vj > 0)  { float fn = sf[v - 1];  int n = v - 1;  if (fn < bf || (fn == bf && n < bi)) { bf = fn; bi = n; } }
    if (vj < 63) { float fn = sf[v + 1];  int n = v + 1;  if (fn < bf || (fn == bf && n < bi)) { bf = fn; bi = n; } }
    if (vi > 0)  { float fn = sf[v - 64]; int n = v - 64; if (fn < bf || (fn == bf && n < bi)) { bf = fn; bi = n; } }
    if (vi < 63) { float fn = sf[v + 64]; int n = v + 64; if (fn < bf || (fn == bf && n < bi)) { bf = fn; bi = n; } }
    srep[v] = bi;
    preg[s] = bi;
  }
  __syncthreads();

  for (int it = 0; it < 12; ++it) {
#pragma unroll 4
    for (int s = 0; s < 4; ++s) {
      int x = srep[preg[s]];
      srep[tid + s * 1024] = x;
      preg[s] = x;
    }
    __syncthreads();
  }

  for (int v = tid; v < NPTS; v += 1024) {
    if (srep[v] == v) {
      int id = atomicAdd(&c_m, 1);
      if (id < IDCAP) { sbasin[v] = id; smu[id] = sf[v]; sminv[id] = v; }
      else sbasin[v] = IDCAP - 1;
    }
  }
  __syncthreads();
  for (int v = tid; v < NPTS; v += 1024) {
    if (srep[v] != v) sbasin[v] = sbasin[srep[v]];
  }
  __syncthreads();

  for (int v = tid; v < NPTS; v += 1024) bas_out[b * NPTS + v] = sbasin[v];
  if (tid < 128) { mu_out[b * 128 + tid] = smu[tid]; mv_out[b * 128 + tid] = sminv[tid]; }
  if (tid == 0) { mm_out[b * 2] = fminb; mm_out[b * 2 + 1] = fmaxb; }
}

// ---------------- Kernel B1: edges + dedup + LDS sort -> sorted list to ws ----------------
__global__ __launch_bounds__(512) void mst_sort_kernel(const float* __restrict__ fin,
                                                       int* __restrict__ bas_io,   // read bas, then alias slist
                                                       int* __restrict__ n2_out) {
  __shared__ float sf[NPTS];
  __shared__ int sbin[NPTS];
  __shared__ unsigned ptable[4096];
  __shared__ __align__(16) u64 slist2[SORTCAP];
  __shared__ int c_l2;

  int b = blockIdx.x;
  int tid = threadIdx.x;
  if (tid == 0) c_l2 = 0;
  for (int v = tid; v < NPTS; v += 512) {
    sf[v] = fin[b * NPTS + v];
    sbin[v] = bas_io[b * NPTS + v];
    ptable[v] = 0xFFFFFFFFu;
  }
  __syncthreads();   // global bas[b] region dead for this block from here

  for (int e = tid; e < NEDGE; e += 512) {
    int u, v2;
    if (e < 4032) { int i = e / 63; int j = e - i * 63; u = (i << 6) | j; v2 = u + 1; }
    else          { int e2 = e - 4032; u = e2; v2 = u + 64; }
    int bu = sbin[u], bv = sbin[v2];
    if (bu != bv) {
      float wgt = fmaxf(sf[u], sf[v2]);
      int a = bu < bv ? bu : bv, bb2 = bu < bv ? bv : bu;
      int t = (bb2 * (bb2 - 1)) / 2 + a;
      atomicMin(&ptable[t], __float_as_uint(wgt));
    }
  }
  __syncthreads();

  for (int t = tid; t < 4096; t += 512) {
    unsigned wv2 = ptable[t];
    if (wv2 != 0xFFFFFFFFu) {
      int bb2 = (int)((1.0f + sqrtf(1.0f + 8.0f * (float)t)) * 0.5f);
      while (bb2 > 1 && (bb2 * (bb2 - 1)) / 2 > t) bb2--;
      while (((bb2 + 1) * bb2) / 2 <= t) bb2++;
      int aa = t - (bb2 * (bb2 - 1)) / 2;
      int slot = atomicAdd(&c_l2, 1);
      if (slot < SORTCAP) slist2[slot] = ((u64)wv2 << 32) | (unsigned)((bb2 << 8) | aa);
    }
  }
  __syncthreads();
  int n2 = c_l2; if (n2 > SORTCAP) n2 = SORTCAP;
  int npad2 = 1; while (npad2 < n2) npad2 <<= 1;
  if (n2 == 0) npad2 = 0;
  for (int i = n2 + tid; i < npad2; i += 512) slist2[i] = ~0ull;
  __syncthreads();

  for (int k = 2; k <= npad2; k <<= 1) {
    for (int j = k >> 1; j > 0; j >>= 1) {
      for (int i = tid; i < npad2; i += 512) {
        int ixj = i ^ j;
        if (ixj > i) {
          u64 x = slist2[i], y = slist2[ixj];
          bool up = ((i & k) == 0);
          if (up ? (x > y) : (x < y)) { slist2[i] = y; slist2[ixj] = x; }
        }
      }
      __syncthreads();
    }
  }

  // write sorted list into the dead bas[b] region
  u64* slout = (u64*)(bas_io + b * NPTS);
  for (int i = tid; i < n2; i += 512) slout[i] = slist2[i];
  if (tid == 0) n2_out[b] = n2;
}

// ---------------- Kernel B2+C: parallel per-wave Kruskal + landscape + MLP ----------------
__global__ __launch_bounds__(256) void final_kernel(const int* __restrict__ bas_io,  // holds slist
                                                    const float* __restrict__ mu_in,
                                                    const int* __restrict__ mv_in,
                                                    const unsigned* __restrict__ mm_in,
                                                    const int* __restrict__ n2_in,
                                                    const float* __restrict__ Wg,
                                                    const float* __restrict__ bg,
                                                    const float* __restrict__ Wfc,
                                                    const float* __restrict__ bfc,
                                                    float* __restrict__ out) {
  __shared__ float2 spairs[2][PAIRCAP];
  __shared__ int snp[2];
  __shared__ float sland[2][50];
  __shared__ float sx[2][50];
  __shared__ float sWg[2500];
  __shared__ float sbg[50];
  __shared__ float sWfc[500];
  __shared__ float sbfc[10];

  int tid = threadIdx.x;
  int wv = tid >> 6, lane = tid & 63;

  if (wv >= 2) {
    // waves 2-3: stage weights while waves 0-1 run Kruskal
    int t = tid - 128;
    for (int i = t; i < 2500; i += 128) sWg[i] = Wg[i];
    for (int i = t; i < 500; i += 128) sWfc[i] = Wfc[i];
    if (t < 50) sbg[t] = bg[t];
    if (t >= 64 && t < 74) sbfc[t - 64] = bfc[t - 64];
  } else {
    // waves 0-1: per-batch serial Kruskal (b = wv), readlane-based
    int b = wv;
    const u64* slist = (const u64*)(bas_io + b * NPTS);
    int n2 = n2_in[b];
    int p0 = lane, p1 = 64 + lane;
    float m0 = mu_in[b * 128 + lane], m1 = mu_in[b * 128 + 64 + lane];
    int r0 = mv_in[b * 128 + lane], r1 = mv_in[b * 128 + 64 + lane];
    int np = 0;
    for (int base = 0; base < n2; base += 64) {
      int idx = base + lane;
      u64 ev = (idx < n2) ? slist[idx] : ~0ull;
      int a_l = (int)(ev & 0xffull);
      int b_l = (int)((ev >> 8) & 0xffull);
      int w_l = (int)(unsigned)(ev >> 32);
      int ra_pre = (a_l < 64) ? __shfl(p0, a_l) : __shfl(p1, a_l & 63);
      int rb_pre = (b_l < 64) ? __shfl(p0, b_l) : __shfl(p1, b_l & 63);
      u64 cand = __ballot((idx < n2) && (ra_pre != rb_pre));
      while (cand) {
        int s = __builtin_ctzll(cand); cand &= cand - 1;
        int a   = rdl(a_l, s);
        int bb2 = rdl(b_l, s);
        int wb  = rdl(w_l, s);
        int ia = a & 63, ib = bb2 & 63;
        int pa = (a < 64)   ? rdl(p0, ia) : rdl(p1, ia);
        int pb = (bb2 < 64) ? rdl(p0, ib) : rdl(p1, ib);
        if (pa == pb) continue;
        float ma = (a < 64)   ? rdlf(m0, ia) : rdlf(m1, ia);
        float mb = (bb2 < 64) ? rdlf(m0, ib) : rdlf(m1, ib);
        int ra = (a < 64)   ? rdl(r0, ia) : rdl(r1, ia);
        int rb = (bb2 < 64) ? rdl(r0, ib) : rdl(r1, ib);
        bool aeld = (ma < mb) || (ma == mb && ra <= rb);
        int eld = aeld ? pa : pb, yng = aeld ? pb : pa;
        float m_e = aeld ? ma : mb; int r_e = aeld ? ra : rb;
        float byoung = aeld ? mb : ma;
        bool h0 = (p0 == yng), h1 = (p1 == yng);
        p0 = h0 ? eld : p0; m0 = h0 ? m_e : m0; r0 = h0 ? r_e : r0;
        p1 = h1 ? eld : p1; m1 = h1 ? m_e : m1; r1 = h1 ? r_e : r1;
        if (lane == 0 && np < PAIRCAP - 1) spairs[b][np] = make_float2(byoung, __uint_as_float((unsigned)wb));
        np++;
      }
    }
    if (np > PAIRCAP - 1) np = PAIRCAP - 1;
    if (lane == 0) {
      spairs[b][np] = make_float2(__uint_as_float(mm_in[b * 2]), __uint_as_float(mm_in[b * 2 + 1]));
      snp[b] = np + 1;
    }
  }
  __syncthreads();

  if (tid < 50) {
    int b = tid / 25, t = tid % 25;
    float tv = 1.875f * (float)t;
    float top1 = 0.f, top2 = 0.f;
    int n = snp[b];
    for (int i = 0; i < n; ++i) {
      float2 p = spairs[b][i];
      float tri = fminf(tv - p.x, p.y - tv);
      tri = fmaxf(tri, 0.f);
      if (tri > top1) { top2 = top1; top1 = tri; }
      else if (tri > top2) top2 = tri;
    }
    sland[b][t] = top1;
    sland[b][25 + t] = top2;
  }
  __syncthreads();
  if (tid < 100) {
    int b = tid / 50, o = tid % 50;
    float acc = sbg[o];
    for (int k = 0; k < 50; ++k) acc += sland[b][k] * sWg[o * 50 + k];
    sx[b][o] = acc;
  }
  __syncthreads();
  if (tid < 50) out[20 + tid] = fabsf(sx[0][tid]) + fabsf(sx[1][tid]);
  if (tid >= 128 && tid < 148) {
    int t2 = tid - 128;
    int b = t2 / 10, c = t2 % 10;
    float acc = sbfc[c];
    for (int o = 0; o < 50; ++o) acc += fmaxf(sx[b][o], 0.f) * sWfc[c * 50 + o];
    out[b * 10 + c] = acc;
  }
}

extern "C" void kernel_launch(void* const* d_in, const int* in_sizes, int n_in,
                              void* d_out, int out_size, void* d_ws, size_t ws_size,
                              hipStream_t stream) {
  (void)in_sizes; (void)n_in; (void)out_size; (void)ws_size;
  const float* input = (const float*)d_in[0];
  const float* Wg  = (const float*)d_in[1];
  const float* bg  = (const float*)d_in[2];
  const float* Wfc = (const float*)d_in[3];
  const float* bfc = (const float*)d_in[4];
  float* out = (float*)d_out;

  char* ws = (char*)d_ws;
  float*    f_ws    = (float*)(ws + F_OFF);
  int*      bas_ws  = (int*)(ws + BAS_OFF);
  float*    mu_ws   = (float*)(ws + MU_OFF);
  int*      mv_ws   = (int*)(ws + MV_OFF);
  unsigned* mm_ws   = (unsigned*)(ws + MM_OFF);
  int*      n2_ws   = (int*)(ws + N2_OFF);

  dtm_kernel<<<dim3(256, 2), 1024, 0, stream>>>(input, f_ws);
  basin_kernel<<<dim3(2), 1024, 0, stream>>>(f_ws, bas_ws, mu_ws, mv_ws, mm_ws);
  mst_sort_kernel<<<dim3(2), 512, 0, stream>>>(f_ws, bas_ws, n2_ws);
  final_kernel<<<1, 256, 0, stream>>>(bas_ws, mu_ws, mv_ws, mm_ws, n2_ws, Wg, bg, Wfc, bfc, out);
}

// Round 13
// 78.165 us; speedup vs baseline: 1.1478x; 1.0046x over previous
//
#include <hip/hip_runtime.h>

#define NPTS 4096
#define NEDGE 8064
#define M0f 0.05f
#define KMAXD2 7938
#define IDCAP 90          // basin-id clamp; triangular pair table needs IDCAP*(IDCAP-1)/2 <= 4096
#define SORTCAP 512
#define PAIRCAP 160

typedef unsigned long long u64;

__device__ inline float waveSum(float x) {
  for (int m = 32; m >= 1; m >>= 1) x += __shfl_xor(x, m);
  return x;
}

__device__ inline int isqrt_i(int x) {  // exact floor sqrt for 0 <= x < 2^20
  int r = (int)sqrtf((float)x);
  if ((r + 1) * (r + 1) <= x) r++;
  else if (r * r > x) r--;
  return r;
}

// uniform-index readlane helpers (index must be wave-uniform SGPR)
__device__ inline int rdl(int v, int l) { return __builtin_amdgcn_readlane(v, l); }
__device__ inline float rdlf(float v, int l) {
  return __uint_as_float((unsigned)__builtin_amdgcn_readlane((int)__float_as_uint(v), l));
}

// ---------------- Kernel 1: DTM (unchanged, galloping) ----------------
__global__ __launch_bounds__(1024) void dtm_kernel(const float* __restrict__ win,
                                                   float* __restrict__ fout) {
  __shared__ float P0[64][65];
  __shared__ float P1[64][65];
  __shared__ float P2[64][65];
  int b = blockIdx.y;
  const float* w = win + b * NPTS;
  int tid = threadIdx.x, lane = tid & 63, wv = tid >> 6;

  for (int rr = 0; rr < 4; ++rr) {
    int r = (wv << 2) | rr;
    float x0 = w[(r << 6) | lane];
    float fl = (float)lane;
    float x1 = x0 * fl, x2 = x1 * fl;
    for (int d = 1; d < 64; d <<= 1) {
      float t0 = __shfl_up(x0, d);
      float t1 = __shfl_up(x1, d);
      float t2 = __shfl_up(x2, d);
      if (lane >= d) { x0 += t0; x1 += t1; x2 += t2; }
    }
    P0[r][lane] = x0; P1[r][lane] = x1; P2[r][lane] = x2;
  }
  __syncthreads();

  float sumw = waveSum(P0[lane][63]);
  float thr = M0f * sumw;

  int q = blockIdx.x * 16 + wv;
  int qi = q >> 6, qj = q & 63;
  int di = qi - lane;
  int disq = di * di;

  auto evalF = [&](int K) -> float {
    float s0 = 0.f;
    int rem = K - disq;
    if (rem >= 0) {
      int r = isqrt_i(rem);
      int l0 = qj - r; l0 = l0 < 0 ? 0 : l0;
      int h0 = qj + r; h0 = h0 > 63 ? 63 : h0;
      s0 = P0[lane][h0] - (l0 > 0 ? P0[lane][l0 - 1] : 0.f);
    }
    return waveSum(s0);
  };

  int lo = -1, hi = 256;
  float Flo = 0.f;
  for (;;) {
    float F = evalF(hi);
    if (F >= thr || hi == KMAXD2) break;
    lo = hi; Flo = F;
    hi = (hi == 256) ? 1024 : KMAXD2;
  }
  while (hi - lo > 1) {
    int mid = (lo + hi) >> 1;
    float F = evalF(mid);
    if (F >= thr) hi = mid; else { lo = mid; Flo = F; }
  }
  int kstar = hi;
  float Fm = Flo;

  float g = 0.f;
  {
    int rem = (kstar - 1) - disq;
    if (rem >= 0) {
      int r = isqrt_i(rem);
      int l0 = qj - r; l0 = l0 < 0 ? 0 : l0;
      int h0 = qj + r; h0 = h0 > 63 ? 63 : h0;
      float S0 = P0[lane][h0] - (l0 > 0 ? P0[lane][l0 - 1] : 0.f);
      float S1 = P1[lane][h0] - (l0 > 0 ? P1[lane][l0 - 1] : 0.f);
      float S2 = P2[lane][h0] - (l0 > 0 ? P2[lane][l0 - 1] : 0.f);
      float fq = (float)qj;
      g = (float)disq * S0 + fq * fq * S0 - 2.f * fq * S1 + S2;
    }
  }
  float G = waveSum(g);
  float val = (G + (thr - Fm) * (float)kstar) / thr;
  val = val < 0.f ? 0.f : val;
  float res = (224.f / 63.f) * sqrtf(val);
  if (lane == 0) fout[b * NPTS + q] = res;
}

// ---------------- Kernel 2: fully fused PH0 + landscape + MLP (1 block per batch) ----------------
__global__ __launch_bounds__(1024) void ph_fused(const float* __restrict__ fin,
                                                 const float* __restrict__ Wg,
                                                 const float* __restrict__ bg,
                                                 const float* __restrict__ Wfc,
                                                 const float* __restrict__ bfc,
                                                 float* __restrict__ out) {
  __shared__ float sf[NPTS];
  __shared__ __align__(16) int srep[NPTS];    // aliased later: unsigned ptable[4096]
  __shared__ __align__(16) int sbasin[NPTS];  // aliased later: u64 slist2[SORTCAP]
  __shared__ float smu[128];
  __shared__ int sminv[128];
  __shared__ float2 spairs[PAIRCAP];
  __shared__ float sland[50];
  __shared__ float sx[50];
  __shared__ float sWg[2500];
  __shared__ float sbg[50];
  __shared__ float sWfc[500];
  __shared__ float sbfc[10];
  __shared__ int c_m, c_l2, c_np;
  __shared__ unsigned fminb, fmaxb;

  int b = blockIdx.x;
  int tid = threadIdx.x;
  int lane = tid & 63;
  if (tid == 0) { c_m = 0; c_l2 = 0; c_np = 0; fminb = 0x7f800000u; fmaxb = 0u; }
  if (tid < 128) { smu[tid] = 3.0e38f; sminv[tid] = tid; }

  // weight prefetch (consumed only at the end; 16 waves hide the latency)
  for (int i = tid; i < 2500; i += 1024) sWg[i] = Wg[i];
  for (int i = tid; i < 500; i += 1024) sWfc[i] = Wfc[i];
  if (tid < 50) sbg[tid] = bg[tid];
  if (tid >= 64 && tid < 74) sbfc[tid - 64] = bfc[tid - 64];

  // load f; per-wave min/max, one LDS atomic per wave
  {
    float lmin = 3.0e38f, lmax = 0.f;
    for (int v = tid; v < NPTS; v += 1024) {
      float x = fin[b * NPTS + v];
      sf[v] = x;
      lmin = fminf(lmin, x);
      lmax = fmaxf(lmax, x);
    }
    for (int m = 32; m >= 1; m >>= 1) {
      lmin = fminf(lmin, __shfl_xor(lmin, m));
      lmax = fmaxf(lmax, __shfl_xor(lmax, m));
    }
    if (lane == 0) {
      atomicMin(&fminb, __float_as_uint(lmin));  // f >= 0: uint order == float order
      atomicMax(&fmaxb, __float_as_uint(lmax));
    }
  }
  __syncthreads();

  // steepest-descent pointers (lexicographic (f, index) tie-break); register copies
  int preg[4];
#pragma unroll 4
  for (int s = 0; s < 4; ++s) {
    int v = tid + s * 1024;
    int vi = v >> 6, vj = v & 63;
    float bf = sf[v]; int bi = v;
    if (vj > 0)  { float fn = sf[v - 1];  int n = v - 1;  if (fn < bf || (fn == bf && n < bi)) { bf = fn; bi = n; } }
    if (vj < 63) { float fn = sf[v + 1];  int n = v + 1;  if (fn < bf || (fn == bf && n < bi)) { bf = fn; bi = n; } }
    if (vi > 0)  { float fn = sf[v - 64]; int n = v - 64; if (fn < bf || (fn == bf && n < bi)) { bf = fn; bi = n; } }
    if (vi < 63) { float fn = sf[v + 64]; int n = v + 64; if (fn < bf || (fn == bf && n < bi)) { bf = fn; bi = n; } }
    srep[v] = bi;
    preg[s] = bi;
  }
  __syncthreads();

  // pointer jumping, 8 double-hop rounds (guaranteed depth 3^8 >= 4096; monotone races benign)
  for (int it = 0; it < 8; ++it) {
#pragma unroll 4
    for (int s = 0; s < 4; ++s) {
      int x = srep[preg[s]];
      x = srep[x];
      srep[tid + s * 1024] = x;
      preg[s] = x;
    }
    __syncthreads();
  }

  // compact basin ids at minima
  for (int v = tid; v < NPTS; v += 1024) {
    if (srep[v] == v) {
      int id = atomicAdd(&c_m, 1);
      if (id < IDCAP) { sbasin[v] = id; smu[id] = sf[v]; sminv[id] = v; }
      else sbasin[v] = IDCAP - 1;
    }
  }
  __syncthreads();
  for (int v = tid; v < NPTS; v += 1024) {
    if (srep[v] != v) sbasin[v] = sbasin[srep[v]];
  }
  __syncthreads();   // srep dead from here

  // dedup via triangular pair table (aliases srep), atomicMin on weight bits
  unsigned* ptable = (unsigned*)srep;
  for (int i = tid; i < 4096; i += 1024) ptable[i] = 0xFFFFFFFFu;
  __syncthreads();
  for (int e = tid; e < NEDGE; e += 1024) {
    int u, v2;
    if (e < 4032) { int i = e / 63; int j = e - i * 63; u = (i << 6) | j; v2 = u + 1; }
    else          { int e2 = e - 4032; u = e2; v2 = u + 64; }
    int bu = sbasin[u], bv = sbasin[v2];
    if (bu != bv) {
      float wgt = fmaxf(sf[u], sf[v2]);
      int a = bu < bv ? bu : bv, bb2 = bu < bv ? bv : bu;
      int t = (bb2 * (bb2 - 1)) / 2 + a;
      atomicMin(&ptable[t], __float_as_uint(wgt));
    }
  }
  __syncthreads();   // sbasin dead from here

  // compact table -> slist2 (aliases sbasin): (w<<32) | (b<<8) | a
  u64* slist2 = (u64*)sbasin;
  for (int t = tid; t < 4096; t += 1024) {
    unsigned wv2 = ptable[t];
    if (wv2 != 0xFFFFFFFFu) {
      int bb2 = (int)((1.0f + sqrtf(1.0f + 8.0f * (float)t)) * 0.5f);
      while (bb2 > 1 && (bb2 * (bb2 - 1)) / 2 > t) bb2--;
      while (((bb2 + 1) * bb2) / 2 <= t) bb2++;
      int aa = t - (bb2 * (bb2 - 1)) / 2;
      int slot = atomicAdd(&c_l2, 1);
      if (slot < SORTCAP) slist2[slot] = ((u64)wv2 << 32) | (unsigned)((bb2 << 8) | aa);
    }
  }
  __syncthreads();
  int n2 = c_l2; if (n2 > SORTCAP) n2 = SORTCAP;
  int npad2 = 1; while (npad2 < n2) npad2 <<= 1;
  if (n2 == 0) npad2 = 0;
  for (int i = n2 + tid; i < npad2; i += 1024) slist2[i] = ~0ull;
  __syncthreads();

  // LDS bitonic sort over npad2 (block-parallel, barriered — proven correct)
  for (int k = 2; k <= npad2; k <<= 1) {
    for (int j = k >> 1; j > 0; j >>= 1) {
      for (int i = tid; i < npad2; i += 1024) {
        int ixj = i ^ j;
        if (ixj > i) {
          u64 x = slist2[i], y = slist2[ixj];
          bool up = ((i & k) == 0);
          if (up ? (x > y) : (x < y)) { slist2[i] = y; slist2[ixj] = x; }
        }
      }
      __syncthreads();
    }
  }

  // wave 0: serial Kruskal via uniform readlane
  if (tid < 64) {
    int p0 = lane, p1 = 64 + lane;
    float m0 = smu[lane], m1 = smu[64 + lane];
    int r0 = sminv[lane], r1 = sminv[64 + lane];
    int np = 0;
    for (int base = 0; base < n2; base += 64) {
      int idx = base + lane;
      u64 ev = (idx < n2) ? slist2[idx] : ~0ull;
      int a_l = (int)(ev & 0xffull);
      int b_l = (int)((ev >> 8) & 0xffull);
      int w_l = (int)(unsigned)(ev >> 32);
      int ra_pre = (a_l < 64) ? __shfl(p0, a_l) : __shfl(p1, a_l & 63);
      int rb_pre = (b_l < 64) ? __shfl(p0, b_l) : __shfl(p1, b_l & 63);
      u64 cand = __ballot((idx < n2) && (ra_pre != rb_pre));
      while (cand) {
        int s = __builtin_ctzll(cand); cand &= cand - 1;
        int a   = rdl(a_l, s);
        int bb2 = rdl(b_l, s);
        int wb  = rdl(w_l, s);
        int ia = a & 63, ib = bb2 & 63;
        int pa = (a < 64)   ? rdl(p0, ia) : rdl(p1, ia);
        int pb = (bb2 < 64) ? rdl(p0, ib) : rdl(p1, ib);
        if (pa == pb) continue;
        float ma = (a < 64)   ? rdlf(m0, ia) : rdlf(m1, ia);
        float mb = (bb2 < 64) ? rdlf(m0, ib) : rdlf(m1, ib);
        int ra = (a < 64)   ? rdl(r0, ia) : rdl(r1, ia);
        int rb = (bb2 < 64) ? rdl(r0, ib) : rdl(r1, ib);
        bool aeld = (ma < mb) || (ma == mb && ra <= rb);
        int eld = aeld ? pa : pb, yng = aeld ? pb : pa;
        float m_e = aeld ? ma : mb; int r_e = aeld ? ra : rb;
        float byoung = aeld ? mb : ma;
        bool h0 = (p0 == yng), h1 = (p1 == yng);
        p0 = h0 ? eld : p0; m0 = h0 ? m_e : m0; r0 = h0 ? r_e : r0;
        p1 = h1 ? eld : p1; m1 = h1 ? m_e : m1; r1 = h1 ? r_e : r1;
        if (lane == 0 && np < PAIRCAP - 1) spairs[np] = make_float2(byoung, __uint_as_float((unsigned)wb));
        np++;
      }
    }
    if (np > PAIRCAP - 1) np = PAIRCAP - 1;
    if (lane == 0) {
      spairs[np] = make_float2(__uint_as_float(fminb), __uint_as_float(fmaxb));  // essential pair
      c_np = np + 1;
    }
  }
  __syncthreads();

  // landscape (top-2 triangles at 25 t's)
  int totp = c_np;
  if (tid < 25) {
    float tv = 1.875f * (float)tid;
    float top1 = 0.f, top2 = 0.f;
    for (int i = 0; i < totp; ++i) {
      float2 p = spairs[i];
      float tri = fminf(tv - p.x, p.y - tv);
      tri = fmaxf(tri, 0.f);
      if (tri > top1) { top2 = top1; top1 = tri; }
      else if (tri > top2) top2 = tri;
    }
    sland[tid] = top1;
    sland[25 + tid] = top2;
  }
  __syncthreads();

  // x = land @ Wg.T + bg
  if (tid < 50) {
    float acc = sbg[tid];
    for (int k = 0; k < 50; ++k) acc += sland[k] * sWg[tid * 50 + k];
    sx[tid] = acc;
  }
  __syncthreads();

  // outputs: signal via global atomicAdd (2 blocks, commutative => deterministic); own FC rows direct
  if (tid < 50) atomicAdd(&out[20 + tid], fabsf(sx[tid]));
  if (tid >= 64 && tid < 74) {
    int c = tid - 64;
    float acc = sbfc[c];
    for (int o = 0; o < 50; ++o) acc += fmaxf(sx[o], 0.f) * sWfc[c * 50 + o];
    out[b * 10 + c] = acc;
  }
}

extern "C" void kernel_launch(void* const* d_in, const int* in_sizes, int n_in,
                              void* d_out, int out_size, void* d_ws, size_t ws_size,
                              hipStream_t stream) {
  (void)in_sizes; (void)n_in; (void)out_size; (void)ws_size;
  const float* input = (const float*)d_in[0];
  const float* Wg  = (const float*)d_in[1];
  const float* bg  = (const float*)d_in[2];
  const float* Wfc = (const float*)d_in[3];
  const float* bfc = (const float*)d_in[4];
  float* out = (float*)d_out;

  float* f_ws = (float*)d_ws;  // 2*4096 f32

  hipMemsetAsync(out, 0, 70 * sizeof(float), stream);  // signal accumulated via atomicAdd
  dtm_kernel<<<dim3(256, 2), 1024, 0, stream>>>(input, f_ws);
  ph_fused<<<dim3(2), 1024, 0, stream>>>(f_ws, Wg, bg, Wfc, bfc, out);
}

// Round 14
// 65.774 us; speedup vs baseline: 1.3641x; 1.1884x over previous
//
#include <hip/hip_runtime.h>

#define NPTS 4096
#define NEDGE 8064
#define M0f 0.05f
#define KMAXD2 7938
#define IDCAP 90          // basin-id clamp; triangular pair table needs IDCAP*(IDCAP-1)/2 <= 4096
#define SORTCAP 512
#define PAIRCAP 160

typedef unsigned long long u64;

__device__ inline float waveSum(float x) {
  for (int m = 32; m >= 1; m >>= 1) x += __shfl_xor(x, m);
  return x;
}

__device__ inline int isqrt_i(int x) {  // exact floor sqrt for 0 <= x < 2^20
  int r = (int)sqrtf((float)x);
  if ((r + 1) * (r + 1) <= x) r++;
  else if (r * r > x) r--;
  return r;
}

// uniform-index readlane helpers
__device__ inline int rdl(int v, int l) { return __builtin_amdgcn_readlane(v, l); }
__device__ inline float rdlf(float v, int l) {
  return __uint_as_float((unsigned)__builtin_amdgcn_readlane((int)__float_as_uint(v), l));
}
__device__ inline u64 rdl64(u64 x, int l) {
  unsigned lo = (unsigned)__builtin_amdgcn_readlane((int)(unsigned)(x & 0xffffffffull), l);
  unsigned hi = (unsigned)__builtin_amdgcn_readlane((int)(unsigned)(x >> 32), l);
  return ((u64)hi << 32) | (u64)lo;
}
// dynamic select from a 128-entry register file split across wave (v0: ids 0-63, v1: 64-127)
__device__ inline int sel2(int v0, int v1, int idx) {
  int x0 = __shfl(v0, idx & 63);
  int x1 = __shfl(v1, idx & 63);
  return (idx < 64) ? x0 : x1;
}
__device__ inline u64 shfl_xor64(u64 x, int m) {
  int lo = __shfl_xor((int)(unsigned)(x & 0xffffffffull), m);
  int hi = __shfl_xor((int)(unsigned)(x >> 32), m);
  return ((u64)(unsigned)hi << 32) | (u64)(unsigned)lo;
}

// in-wave bitonic compare-exchange (element i = R*64 + lane)
#define CXL(R, J, K) { \
  u64 vo = shfl_xor64(e##R, J); \
  bool up = (((((R) * 64) & (K)) | (lane & (K))) == 0); \
  bool lower = ((lane & (J)) == 0); \
  bool kmin = (lower == up); \
  u64 mn = (e##R < vo) ? e##R : vo; \
  u64 mx = (e##R < vo) ? vo : e##R; \
  e##R = kmin ? mn : mx; }
#define ALL2(J, K) CXL(0,J,K) CXL(1,J,K)
#define CXR(RA, RB, K) { \
  const bool up = ((((RA) * 64) & (K)) == 0); \
  u64 va = e##RA, vb = e##RB; \
  u64 mn = (va < vb) ? va : vb; \
  u64 mx = (va < vb) ? vb : va; \
  e##RA = up ? mn : mx; e##RB = up ? mx : mn; }

// ---------------- Kernel 1: DTM (galloping) + out-zero ----------------
__global__ __launch_bounds__(1024) void dtm_kernel(const float* __restrict__ win,
                                                   float* __restrict__ fout,
                                                   float* __restrict__ out) {
  __shared__ float P0[64][65];
  __shared__ float P1[64][65];
  __shared__ float P2[64][65];
  int b = blockIdx.y;
  const float* w = win + b * NPTS;
  int tid = threadIdx.x, lane = tid & 63, wv = tid >> 6;

  if (blockIdx.x == 0 && blockIdx.y == 0 && tid < 50) out[20 + tid] = 0.f;  // signal accum base

  for (int rr = 0; rr < 4; ++rr) {
    int r = (wv << 2) | rr;
    float x0 = w[(r << 6) | lane];
    float fl = (float)lane;
    float x1 = x0 * fl, x2 = x1 * fl;
    for (int d = 1; d < 64; d <<= 1) {
      float t0 = __shfl_up(x0, d);
      float t1 = __shfl_up(x1, d);
      float t2 = __shfl_up(x2, d);
      if (lane >= d) { x0 += t0; x1 += t1; x2 += t2; }
    }
    P0[r][lane] = x0; P1[r][lane] = x1; P2[r][lane] = x2;
  }
  __syncthreads();

  float sumw = waveSum(P0[lane][63]);
  float thr = M0f * sumw;

  int q = blockIdx.x * 16 + wv;
  int qi = q >> 6, qj = q & 63;
  int di = qi - lane;
  int disq = di * di;

  auto evalF = [&](int K) -> float {
    float s0 = 0.f;
    int rem = K - disq;
    if (rem >= 0) {
      int r = isqrt_i(rem);
      int l0 = qj - r; l0 = l0 < 0 ? 0 : l0;
      int h0 = qj + r; h0 = h0 > 63 ? 63 : h0;
      s0 = P0[lane][h0] - (l0 > 0 ? P0[lane][l0 - 1] : 0.f);
    }
    return waveSum(s0);
  };

  int lo = -1, hi = 256;
  float Flo = 0.f;
  for (;;) {
    float F = evalF(hi);
    if (F >= thr || hi == KMAXD2) break;
    lo = hi; Flo = F;
    hi = (hi == 256) ? 1024 : KMAXD2;
  }
  while (hi - lo > 1) {
    int mid = (lo + hi) >> 1;
    float F = evalF(mid);
    if (F >= thr) hi = mid; else { lo = mid; Flo = F; }
  }
  int kstar = hi;
  float Fm = Flo;

  float g = 0.f;
  {
    int rem = (kstar - 1) - disq;
    if (rem >= 0) {
      int r = isqrt_i(rem);
      int l0 = qj - r; l0 = l0 < 0 ? 0 : l0;
      int h0 = qj + r; h0 = h0 > 63 ? 63 : h0;
      float S0 = P0[lane][h0] - (l0 > 0 ? P0[lane][l0 - 1] : 0.f);
      float S1 = P1[lane][h0] - (l0 > 0 ? P1[lane][l0 - 1] : 0.f);
      float S2 = P2[lane][h0] - (l0 > 0 ? P2[lane][l0 - 1] : 0.f);
      float fq = (float)qj;
      g = (float)disq * S0 + fq * fq * S0 - 2.f * fq * S1 + S2;
    }
  }
  float G = waveSum(g);
  float val = (G + (thr - Fm) * (float)kstar) / thr;
  val = val < 0.f ? 0.f : val;
  float res = (224.f / 63.f) * sqrtf(val);
  if (lane == 0) fout[b * NPTS + q] = res;
}

// ---------------- Kernel 2: fused PH0 (Boruvka) + landscape + MLP ----------------
__global__ __launch_bounds__(1024) void ph_fused(const float* __restrict__ fin,
                                                 const float* __restrict__ Wg,
                                                 const float* __restrict__ bg,
                                                 const float* __restrict__ Wfc,
                                                 const float* __restrict__ bfc,
                                                 float* __restrict__ out) {
  __shared__ float sf[NPTS];
  __shared__ __align__(16) int srep[NPTS];    // aliased later: unsigned ptable[4096]
  __shared__ __align__(16) int sbasin[NPTS];  // aliased later: u64 slist2[SORTCAP]
  __shared__ float smu[128];
  __shared__ int sminv[128];
  __shared__ float2 spairs[PAIRCAP];
  __shared__ float sland[50];
  __shared__ float sx[50];
  __shared__ float sWg[2500];
  __shared__ float sbg[50];
  __shared__ float sWfc[500];
  __shared__ float sbfc[10];
  __shared__ int comparr[128];
  __shared__ unsigned minW[128], minI[128];
  __shared__ u64 mstlist[128];
  __shared__ int c_m, c_l2, c_np, c_hook;
  __shared__ unsigned fminb, fmaxb;

  int b = blockIdx.x;
  int tid = threadIdx.x;
  int lane = tid & 63;
  if (tid == 0) { c_m = 0; c_l2 = 0; c_np = 0; fminb = 0x7f800000u; fmaxb = 0u; }
  if (tid < 128) { smu[tid] = 3.0e38f; sminv[tid] = tid; mstlist[tid] = ~0ull; }

  // weight prefetch (consumed at the end)
  for (int i = tid; i < 2500; i += 1024) sWg[i] = Wg[i];
  for (int i = tid; i < 500; i += 1024) sWfc[i] = Wfc[i];
  if (tid < 50) sbg[tid] = bg[tid];
  if (tid >= 64 && tid < 74) sbfc[tid - 64] = bfc[tid - 64];

  // load f; per-wave min/max
  {
    float lmin = 3.0e38f, lmax = 0.f;
    for (int v = tid; v < NPTS; v += 1024) {
      float x = fin[b * NPTS + v];
      sf[v] = x;
      lmin = fminf(lmin, x);
      lmax = fmaxf(lmax, x);
    }
    for (int m = 32; m >= 1; m >>= 1) {
      lmin = fminf(lmin, __shfl_xor(lmin, m));
      lmax = fmaxf(lmax, __shfl_xor(lmax, m));
    }
    if (lane == 0) {
      atomicMin(&fminb, __float_as_uint(lmin));
      atomicMax(&fmaxb, __float_as_uint(lmax));
    }
  }
  __syncthreads();

  // steepest-descent pointers
  int preg[4];
#pragma unroll 4
  for (int s = 0; s < 4; ++s) {
    int v = tid + s * 1024;
    int vi = v >> 6, vj = v & 63;
    float bf = sf[v]; int bi = v;
    if (vj > 0)  { float fn = sf[v - 1];  int n = v - 1;  if (fn < bf || (fn == bf && n < bi)) { bf = fn; bi = n; } }
    if (vj < 63) { float fn = sf[v + 1];  int n = v + 1;  if (fn < bf || (fn == bf && n < bi)) { bf = fn; bi = n; } }
    if (vi > 0)  { float fn = sf[v - 64]; int n = v - 64; if (fn < bf || (fn == bf && n < bi)) { bf = fn; bi = n; } }
    if (vi < 63) { float fn = sf[v + 64]; int n = v + 64; if (fn < bf || (fn == bf && n < bi)) { bf = fn; bi = n; } }
    srep[v] = bi;
    preg[s] = bi;
  }
  __syncthreads();

  // pointer jumping, 8 double-hop rounds
  for (int it = 0; it < 8; ++it) {
#pragma unroll 4
    for (int s = 0; s < 4; ++s) {
      int x = srep[preg[s]];
      x = srep[x];
      srep[tid + s * 1024] = x;
      preg[s] = x;
    }
    __syncthreads();
  }

  // compact basin ids at minima
  for (int v = tid; v < NPTS; v += 1024) {
    if (srep[v] == v) {
      int id = atomicAdd(&c_m, 1);
      if (id < IDCAP) { sbasin[v] = id; smu[id] = sf[v]; sminv[id] = v; }
      else sbasin[v] = IDCAP - 1;
    }
  }
  __syncthreads();
  for (int v = tid; v < NPTS; v += 1024) {
    if (srep[v] != v) sbasin[v] = sbasin[srep[v]];
  }
  __syncthreads();   // srep dead

  // dedup via triangular pair table (aliases srep)
  unsigned* ptable = (unsigned*)srep;
  for (int i = tid; i < 4096; i += 1024) ptable[i] = 0xFFFFFFFFu;
  __syncthreads();
  for (int e = tid; e < NEDGE; e += 1024) {
    int u, v2;
    if (e < 4032) { int i = e / 63; int j = e - i * 63; u = (i << 6) | j; v2 = u + 1; }
    else          { int e2 = e - 4032; u = e2; v2 = u + 64; }
    int bu = sbasin[u], bv = sbasin[v2];
    if (bu != bv) {
      float wgt = fmaxf(sf[u], sf[v2]);
      int a = bu < bv ? bu : bv, bb2 = bu < bv ? bv : bu;
      int t = (bb2 * (bb2 - 1)) / 2 + a;
      atomicMin(&ptable[t], __float_as_uint(wgt));
    }
  }
  __syncthreads();   // sbasin dead

  // compact table -> slist2 (aliases sbasin): (w<<32) | (b<<8) | a
  u64* slist2 = (u64*)sbasin;
  for (int t = tid; t < 4096; t += 1024) {
    unsigned wv2 = ptable[t];
    if (wv2 != 0xFFFFFFFFu) {
      int bb2 = (int)((1.0f + sqrtf(1.0f + 8.0f * (float)t)) * 0.5f);
      while (bb2 > 1 && (bb2 * (bb2 - 1)) / 2 > t) bb2--;
      while (((bb2 + 1) * bb2) / 2 <= t) bb2++;
      int aa = t - (bb2 * (bb2 - 1)) / 2;
      int slot = atomicAdd(&c_l2, 1);
      if (slot < SORTCAP) slist2[slot] = ((u64)wv2 << 32) | (unsigned)((bb2 << 8) | aa);
    }
  }
  __syncthreads();
  int n2 = c_l2; if (n2 > SORTCAP) n2 = SORTCAP;

  // ---- Boruvka contraction: MST edges -> mstlist, count nmst (wave0 registers) ----
  int comp0 = lane, comp1 = 64 + lane;   // meaningful in wave0 only
  int nmst = 0;
  for (int round = 0; round < 8; ++round) {
    if (tid < 64) {
      comparr[lane] = comp0; comparr[64 + lane] = comp1;
      minW[lane] = 0xFFFFFFFFu; minW[64 + lane] = 0xFFFFFFFFu;
      minI[lane] = 0xFFFFFFFFu; minI[64 + lane] = 0xFFFFFFFFu;
      if (lane == 0) c_hook = 0;
    }
    __syncthreads();
    for (int e = tid; e < n2; e += 1024) {
      u64 ev = slist2[e];
      int a = (int)(ev & 0xffull), bb2 = (int)((ev >> 8) & 0xffull);
      int ra = comparr[a], rb = comparr[bb2];
      if (ra != rb) {
        unsigned w = (unsigned)(ev >> 32);
        atomicMin(&minW[ra], w);
        atomicMin(&minW[rb], w);
      }
    }
    __syncthreads();
    for (int e = tid; e < n2; e += 1024) {
      u64 ev = slist2[e];
      int a = (int)(ev & 0xffull), bb2 = (int)((ev >> 8) & 0xffull);
      int ra = comparr[a], rb = comparr[bb2];
      if (ra != rb) {
        unsigned w = (unsigned)(ev >> 32);
        if (w == minW[ra]) atomicMin(&minI[ra], (unsigned)e);
        if (w == minW[rb]) atomicMin(&minI[rb], (unsigned)e);
      }
    }
    __syncthreads();
    if (tid < 64) {
      unsigned mi0 = minI[lane], mi1 = minI[64 + lane];
      u64 ev0 = (mi0 != 0xFFFFFFFFu) ? slist2[mi0] : 0ull;
      u64 ev1 = (mi1 != 0xFFFFFFFFu) ? slist2[mi1] : 0ull;
      int a0 = (int)(ev0 & 0xffull), b0 = (int)((ev0 >> 8) & 0xffull);
      int a1 = (int)(ev1 & 0xffull), b1 = (int)((ev1 >> 8) & 0xffull);
      int raA = sel2(comp0, comp1, a0), rbA = sel2(comp0, comp1, b0);
      int raB = sel2(comp0, comp1, a1), rbB = sel2(comp0, comp1, b1);
      int parA0 = (mi0 != 0xFFFFFFFFu) ? ((raA == lane) ? rbA : raA) : lane;
      int parA1 = (mi1 != 0xFFFFFFFFu) ? ((raB == 64 + lane) ? rbB : raB) : (64 + lane);
      // 2-cycle resolve (distinct (w,idx) keys => only 2-cycles possible)
      int pp0 = sel2(parA0, parA1, parA0);
      int pp1 = sel2(parA0, parA1, parA1);
      int par0 = (pp0 == lane && lane < parA0) ? lane : parA0;
      int par1 = (pp1 == (64 + lane) && (64 + lane) < parA1) ? (64 + lane) : parA1;
      // collect MST edges (hooker contributes its edge), deterministic by id
      bool h0 = (par0 != lane);
      bool h1 = (par1 != (64 + lane));
      u64 mlo = __ballot(h0);
      int cnt0 = __popcll(mlo);
      int pos0 = nmst + __popcll(mlo & ((1ull << lane) - 1ull));
      if (h0 && pos0 < 128) mstlist[pos0] = ev0;
      u64 mhi = __ballot(h1);
      int pos1 = nmst + cnt0 + __popcll(mhi & ((1ull << lane) - 1ull));
      if (h1 && pos1 < 128) mstlist[pos1] = ev1;
      int tot = cnt0 + __popcll(mhi);
      nmst += tot;
      if (lane == 0 && tot > 0) c_hook = 1;
      // compress par (early-exit jumping), then update comp
      for (int j = 0; j < 8; ++j) {
        int n0 = sel2(par0, par1, par0);
        int n1 = sel2(par0, par1, par1);
        bool ch = (n0 != par0) || (n1 != par1);
        par0 = n0; par1 = n1;
        if (__ballot(ch) == 0ull) break;
      }
      comp0 = sel2(par0, par1, comp0);
      comp1 = sel2(par0, par1, comp1);
    }
    __syncthreads();
    if (c_hook == 0) break;
  }

  // ---- wave0: in-register sort of <=128 MST edges + serial readlane Kruskal ----
  if (tid < 64) {
    u64 e0 = mstlist[lane], e1 = mstlist[64 + lane];
    ALL2(1,2)
    ALL2(2,4) ALL2(1,4)
    ALL2(4,8) ALL2(2,8) ALL2(1,8)
    ALL2(8,16) ALL2(4,16) ALL2(2,16) ALL2(1,16)
    ALL2(16,32) ALL2(8,32) ALL2(4,32) ALL2(2,32) ALL2(1,32)
    ALL2(32,64) ALL2(16,64) ALL2(8,64) ALL2(4,64) ALL2(2,64) ALL2(1,64)
    CXR(0,1,128)
    ALL2(32,128) ALL2(16,128) ALL2(8,128) ALL2(4,128) ALL2(2,128) ALL2(1,128)

    int p0 = lane, p1 = 64 + lane;
    float m0 = smu[lane], m1 = smu[64 + lane];
    int r0 = sminv[lane], r1 = sminv[64 + lane];
    int np = 0;
    for (int s = 0; s < nmst; ++s) {
      u64 ev = (s < 64) ? rdl64(e0, s) : rdl64(e1, s - 64);
      int a = (int)(ev & 0xffull), bb2 = (int)((ev >> 8) & 0xffull);
      unsigned wb = (unsigned)(ev >> 32);
      int ia = a & 63, ib = bb2 & 63;
      int pa = (a < 64) ? rdl(p0, ia) : rdl(p1, ia);
      int pb = (bb2 < 64) ? rdl(p0, ib) : rdl(p1, ib);
      if (pa == pb) continue;  // MST edges never cycle; insurance
      float ma = (a < 64) ? rdlf(m0, ia) : rdlf(m1, ia);
      float mb = (bb2 < 64) ? rdlf(m0, ib) : rdlf(m1, ib);
      int ra = (a < 64) ? rdl(r0, ia) : rdl(r1, ia);
      int rb = (bb2 < 64) ? rdl(r0, ib) : rdl(r1, ib);
      bool aeld = (ma < mb) || (ma == mb && ra <= rb);
      int eld = aeld ? pa : pb, yng = aeld ? pb : pa;
      float m_e = aeld ? ma : mb; int r_e = aeld ? ra : rb;
      float byoung = aeld ? mb : ma;
      bool g0 = (p0 == yng), g1 = (p1 == yng);
      p0 = g0 ? eld : p0; m0 = g0 ? m_e : m0; r0 = g0 ? r_e : r0;
      p1 = g1 ? eld : p1; m1 = g1 ? m_e : m1; r1 = g1 ? r_e : r1;
      if (lane == 0 && np < PAIRCAP - 1) spairs[np] = make_float2(byoung, __uint_as_float(wb));
      np++;
    }
    if (np > PAIRCAP - 1) np = PAIRCAP - 1;
    if (lane == 0) {
      spairs[np] = make_float2(__uint_as_float(fminb), __uint_as_float(fmaxb));  // essential pair
      c_np = np + 1;
    }
  }
  __syncthreads();

  // landscape (top-2 triangles at 25 t's)
  int totp = c_np;
  if (tid < 25) {
    float tv = 1.875f * (float)tid;
    float top1 = 0.f, top2 = 0.f;
    for (int i = 0; i < totp; ++i) {
      float2 p = spairs[i];
      float tri = fminf(tv - p.x, p.y - tv);
      tri = fmaxf(tri, 0.f);
      if (tri > top1) { top2 = top1; top1 = tri; }
      else if (tri > top2) top2 = tri;
    }
    sland[tid] = top1;
    sland[25 + tid] = top2;
  }
  __syncthreads();

  // x = land @ Wg.T + bg
  if (tid < 50) {
    float acc = sbg[tid];
    for (int k = 0; k < 50; ++k) acc += sland[k] * sWg[tid * 50 + k];
    sx[tid] = acc;
  }
  __syncthreads();

  // outputs
  if (tid < 50) atomicAdd(&out[20 + tid], fabsf(sx[tid]));
  if (tid >= 64 && tid < 74) {
    int c = tid - 64;
    float acc = sbfc[c];
    for (int o = 0; o < 50; ++o) acc += fmaxf(sx[o], 0.f) * sWfc[c * 50 + o];
    out[b * 10 + c] = acc;
  }
}

extern "C" void kernel_launch(void* const* d_in, const int* in_sizes, int n_in,
                              void* d_out, int out_size, void* d_ws, size_t ws_size,
                              hipStream_t stream) {
  (void)in_sizes; (void)n_in; (void)out_size; (void)ws_size;
  const float* input = (const float*)d_in[0];
  const float* Wg  = (const float*)d_in[1];
  const float* bg  = (const float*)d_in[2];
  const float* Wfc = (const float*)d_in[3];
  const float* bfc = (const float*)d_in[4];
  float* out = (float*)d_out;

  float* f_ws = (float*)d_ws;  // 2*4096 f32

  dtm_kernel<<<dim3(256, 2), 1024, 0, stream>>>(input, f_ws, out);
  ph_fused<<<dim3(2), 1024, 0, stream>>>(f_ws, Wg, bg, Wfc, bfc, out);
}

// Round 16
// 62.853 us; speedup vs baseline: 1.4274x; 1.0465x over previous
//
#include <hip/hip_runtime.h>

#define NPTS 4096
#define NEDGE 8064
#define M0f 0.05f
#define KMAXD2 7938
#define IDCAP 90          // basin-id clamp; triangular pair table needs IDCAP*(IDCAP-1)/2 <= 4096
#define SORTCAP 512
#define PAIRCAP 160

typedef unsigned long long u64;

__device__ inline float waveSum(float x) {
  for (int m = 32; m >= 1; m >>= 1) x += __shfl_xor(x, m);
  return x;
}

__device__ inline int isqrt_i(int x) {  // exact floor sqrt for 0 <= x < 2^20
  int r = (int)sqrtf((float)x);
  if ((r + 1) * (r + 1) <= x) r++;
  else if (r * r > x) r--;
  return r;
}

// uniform-index readlane helpers
__device__ inline int rdl(int v, int l) { return __builtin_amdgcn_readlane(v, l); }
__device__ inline float rdlf(float v, int l) {
  return __uint_as_float((unsigned)__builtin_amdgcn_readlane((int)__float_as_uint(v), l));
}
__device__ inline u64 rdl64(u64 x, int l) {
  unsigned lo = (unsigned)__builtin_amdgcn_readlane((int)(unsigned)(x & 0xffffffffull), l);
  unsigned hi = (unsigned)__builtin_amdgcn_readlane((int)(unsigned)(x >> 32), l);
  return ((u64)hi << 32) | (u64)lo;
}
// dynamic select from a 128-entry register file split across wave (v0: ids 0-63, v1: 64-127)
__device__ inline int sel2(int v0, int v1, int idx) {
  int x0 = __shfl(v0, idx & 63);
  int x1 = __shfl(v1, idx & 63);
  return (idx < 64) ? x0 : x1;
}
__device__ inline u64 shfl_xor64(u64 x, int m) {
  int lo = __shfl_xor((int)(unsigned)(x & 0xffffffffull), m);
  int hi = __shfl_xor((int)(unsigned)(x >> 32), m);
  return ((u64)(unsigned)hi << 32) | (u64)(unsigned)lo;
}

// in-wave bitonic compare-exchange (element i = R*64 + lane)
#define CXL(R, J, K) { \
  u64 vo = shfl_xor64(e##R, J); \
  bool up = (((((R) * 64) & (K)) | (lane & (K))) == 0); \
  bool lower = ((lane & (J)) == 0); \
  bool kmin = (lower == up); \
  u64 mn = (e##R < vo) ? e##R : vo; \
  u64 mx = (e##R < vo) ? vo : e##R; \
  e##R = kmin ? mn : mx; }
#define ALL2(J, K) CXL(0,J,K) CXL(1,J,K)
#define CXR(RA, RB, K) { \
  const bool up = ((((RA) * 64) & (K)) == 0); \
  u64 va = e##RA, vb = e##RB; \
  u64 mn = (va < vb) ? va : vb; \
  u64 mx = (va < vb) ? vb : va; \
  e##RA = up ? mn : mx; e##RB = up ? mx : mn; }

// ---------------- Kernel 1: DTM (galloping) + out-zero ----------------
__global__ __launch_bounds__(1024) void dtm_kernel(const float* __restrict__ win,
                                                   float* __restrict__ fout,
                                                   float* __restrict__ out) {
  __shared__ float P0[64][65];
  __shared__ float P1[64][65];
  __shared__ float P2[64][65];
  int b = blockIdx.y;
  const float* w = win + b * NPTS;
  int tid = threadIdx.x, lane = tid & 63, wv = tid >> 6;

  if (blockIdx.x == 0 && blockIdx.y == 0 && tid < 50) out[20 + tid] = 0.f;  // signal accum base

  for (int rr = 0; rr < 4; ++rr) {
    int r = (wv << 2) | rr;
    float x0 = w[(r << 6) | lane];
    float fl = (float)lane;
    float x1 = x0 * fl, x2 = x1 * fl;
    for (int d = 1; d < 64; d <<= 1) {
      float t0 = __shfl_up(x0, d);
      float t1 = __shfl_up(x1, d);
      float t2 = __shfl_up(x2, d);
      if (lane >= d) { x0 += t0; x1 += t1; x2 += t2; }
    }
    P0[r][lane] = x0; P1[r][lane] = x1; P2[r][lane] = x2;
  }
  __syncthreads();

  float sumw = waveSum(P0[lane][63]);
  float thr = M0f * sumw;

  int q = blockIdx.x * 16 + wv;
  int qi = q >> 6, qj = q & 63;
  int di = qi - lane;
  int disq = di * di;

  auto evalF = [&](int K) -> float {
    float s0 = 0.f;
    int rem = K - disq;
    if (rem >= 0) {
      int r = isqrt_i(rem);
      int l0 = qj - r; l0 = l0 < 0 ? 0 : l0;
      int h0 = qj + r; h0 = h0 > 63 ? 63 : h0;
      s0 = P0[lane][h0] - (l0 > 0 ? P0[lane][l0 - 1] : 0.f);
    }
    return waveSum(s0);
  };

  int lo = -1, hi = 256;
  float Flo = 0.f;
  for (;;) {
    float F = evalF(hi);
    if (F >= thr || hi == KMAXD2) break;
    lo = hi; Flo = F;
    hi = (hi == 256) ? 1024 : KMAXD2;
  }
  while (hi - lo > 1) {
    int mid = (lo + hi) >> 1;
    float F = evalF(mid);
    if (F >= thr) hi = mid; else { lo = mid; Flo = F; }
  }
  int kstar = hi;
  float Fm = Flo;

  float g = 0.f;
  {
    int rem = (kstar - 1) - disq;
    if (rem >= 0) {
      int r = isqrt_i(rem);
      int l0 = qj - r; l0 = l0 < 0 ? 0 : l0;
      int h0 = qj + r; h0 = h0 > 63 ? 63 : h0;
      float S0 = P0[lane][h0] - (l0 > 0 ? P0[lane][l0 - 1] : 0.f);
      float S1 = P1[lane][h0] - (l0 > 0 ? P1[lane][l0 - 1] : 0.f);
      float S2 = P2[lane][h0] - (l0 > 0 ? P2[lane][l0 - 1] : 0.f);
      float fq = (float)qj;
      g = (float)disq * S0 + fq * fq * S0 - 2.f * fq * S1 + S2;
    }
  }
  float G = waveSum(g);
  float val = (G + (thr - Fm) * (float)kstar) / thr;
  val = val < 0.f ? 0.f : val;
  float res = (224.f / 63.f) * sqrtf(val);
  if (lane == 0) fout[b * NPTS + q] = res;
}

// ---------------- Kernel 2: fused PH0 (Boruvka) + landscape + MLP ----------------
__global__ __launch_bounds__(1024) void ph_fused(const float* __restrict__ fin,
                                                 const float* __restrict__ Wg,
                                                 const float* __restrict__ bg,
                                                 const float* __restrict__ Wfc,
                                                 const float* __restrict__ bfc,
                                                 float* __restrict__ out) {
  __shared__ __align__(16) float sf[NPTS];
  __shared__ __align__(16) int srep[NPTS];    // aliased later: unsigned ptable[4096]
  __shared__ __align__(16) int sbasin[NPTS];  // aliased later: u64 slist2[SORTCAP]
  __shared__ float smu[128];
  __shared__ int sminv[128];
  __shared__ float2 spairs[PAIRCAP];
  __shared__ float sland[50];
  __shared__ float sx[50];
  __shared__ __align__(16) float sWg[2500];
  __shared__ float sbg[50];
  __shared__ __align__(16) float sWfc[500];
  __shared__ float sbfc[10];
  __shared__ int comparr[128];
  __shared__ u64 minKey[128];
  __shared__ u64 mstlist[128];
  __shared__ int c_m, c_np, c_hook, c_chg;
  __shared__ unsigned fminb, fmaxb;
  __shared__ int c_l2;

  int b = blockIdx.x;
  int tid = threadIdx.x;
  int lane = tid & 63;
  if (tid == 0) { c_m = 0; c_l2 = 0; c_np = 0; c_chg = 0; fminb = 0x7f800000u; fmaxb = 0u; }
  if (tid < 128) { smu[tid] = 3.0e38f; sminv[tid] = tid; mstlist[tid] = ~0ull; }

  // weight prefetch, vectorized (consumed at the end)
  if (tid < 625) ((float4*)sWg)[tid] = ((const float4*)Wg)[tid];
  if (tid < 125) ((float4*)sWfc)[tid] = ((const float4*)Wfc)[tid];
  if (tid < 50) sbg[tid] = bg[tid];
  if (tid >= 64 && tid < 74) sbfc[tid - 64] = bfc[tid - 64];

  // load f (float4), per-wave min/max
  {
    float4 v4 = ((const float4*)(fin + b * NPTS))[tid];
    ((float4*)sf)[tid] = v4;
    float lmin = fminf(fminf(v4.x, v4.y), fminf(v4.z, v4.w));
    float lmax = fmaxf(fmaxf(v4.x, v4.y), fmaxf(v4.z, v4.w));
    for (int m = 32; m >= 1; m >>= 1) {
      lmin = fminf(lmin, __shfl_xor(lmin, m));
      lmax = fmaxf(lmax, __shfl_xor(lmax, m));
    }
    if (lane == 0) {
      atomicMin(&fminb, __float_as_uint(lmin));
      atomicMax(&fmaxb, __float_as_uint(lmax));
    }
  }
  __syncthreads();

  // steepest-descent pointers
  int preg[4];
#pragma unroll 4
  for (int s = 0; s < 4; ++s) {
    int v = tid + s * 1024;
    int vi = v >> 6, vj = v & 63;
    float bf = sf[v]; int bi = v;
    if (vj > 0)  { float fn = sf[v - 1];  int n = v - 1;  if (fn < bf || (fn == bf && n < bi)) { bf = fn; bi = n; } }
    if (vj < 63) { float fn = sf[v + 1];  int n = v + 1;  if (fn < bf || (fn == bf && n < bi)) { bf = fn; bi = n; } }
    if (vi > 0)  { float fn = sf[v - 64]; int n = v - 64; if (fn < bf || (fn == bf && n < bi)) { bf = fn; bi = n; } }
    if (vi < 63) { float fn = sf[v + 64]; int n = v + 64; if (fn < bf || (fn == bf && n < bi)) { bf = fn; bi = n; } }
    srep[v] = bi;
    preg[s] = bi;
  }
  __syncthreads();

  // pointer jumping, double-hop, early-exit via round-stamped flag (benign same-value races)
  for (int it = 0; it < 8; ++it) {
    bool ch = false;
#pragma unroll 4
    for (int s = 0; s < 4; ++s) {
      int x = srep[preg[s]];
      x = srep[x];
      ch |= (x != preg[s]);
      srep[tid + s * 1024] = x;
      preg[s] = x;
    }
    u64 bl = __ballot(ch);
    if (lane == 0 && bl != 0ull) c_chg = it + 1;
    __syncthreads();
    if (c_chg != it + 1) break;   // nobody changed this round -> all at roots
  }

  // compact basin ids at minima
  for (int v = tid; v < NPTS; v += 1024) {
    if (srep[v] == v) {
      int id = atomicAdd(&c_m, 1);
      if (id < IDCAP) { sbasin[v] = id; smu[id] = sf[v]; sminv[id] = v; }
      else sbasin[v] = IDCAP - 1;
    }
  }
  __syncthreads();
  for (int v = tid; v < NPTS; v += 1024) {
    if (srep[v] != v) sbasin[v] = sbasin[srep[v]];
  }
  __syncthreads();   // srep dead

  // dedup via triangular pair table (aliases srep)
  unsigned* ptable = (unsigned*)srep;
  for (int i = tid; i < 4096; i += 1024) ptable[i] = 0xFFFFFFFFu;
  __syncthreads();
  for (int e = tid; e < NEDGE; e += 1024) {
    int u, v2;
    if (e < 4032) { int i = e / 63; int j = e - i * 63; u = (i << 6) | j; v2 = u + 1; }
    else          { int e2 = e - 4032; u = e2; v2 = u + 64; }
    int bu = sbasin[u], bv = sbasin[v2];
    if (bu != bv) {
      float wgt = fmaxf(sf[u], sf[v2]);
      int a = bu < bv ? bu : bv, bb2 = bu < bv ? bv : bu;
      int t = (bb2 * (bb2 - 1)) / 2 + a;
      atomicMin(&ptable[t], __float_as_uint(wgt));
    }
  }
  __syncthreads();   // sbasin dead

  // compact table -> slist2 (aliases sbasin): (w<<32) | (b<<8) | a
  u64* slist2 = (u64*)sbasin;
  for (int t = tid; t < 4096; t += 1024) {
    unsigned wv2 = ptable[t];
    if (wv2 != 0xFFFFFFFFu) {
      int bb2 = (int)((1.0f + sqrtf(1.0f + 8.0f * (float)t)) * 0.5f);
      while (bb2 > 1 && (bb2 * (bb2 - 1)) / 2 > t) bb2--;
      while (((bb2 + 1) * bb2) / 2 <= t) bb2++;
      int aa = t - (bb2 * (bb2 - 1)) / 2;
      int slot = atomicAdd(&c_l2, 1);
      if (slot < SORTCAP) slist2[slot] = ((u64)wv2 << 32) | (unsigned)((bb2 << 8) | aa);
    }
  }
  __syncthreads();
  int n2 = c_l2; if (n2 > SORTCAP) n2 = SORTCAP;

  // ---- Boruvka contraction, single-pass min-edge via u64 atomicMin on (w, edge_idx) ----
  int comp0 = lane, comp1 = 64 + lane;   // meaningful in wave0 only
  int nmst = 0;
  for (int round = 0; round < 7; ++round) {
    if (tid < 64) {
      comparr[lane] = comp0; comparr[64 + lane] = comp1;
      if (lane == 0) c_hook = 0;
    }
    if (tid < 128) minKey[tid] = ~0ull;
    __syncthreads();
    for (int e = tid; e < n2; e += 1024) {
      u64 ev = slist2[e];
      int a = (int)(ev & 0xffull), bb2 = (int)((ev >> 8) & 0xffull);
      int ra = comparr[a], rb = comparr[bb2];
      if (ra != rb) {
        u64 key = (ev & 0xFFFFFFFF00000000ull) | (u64)(unsigned)e;  // (w, idx): total order
        atomicMin(&minKey[ra], key);
        atomicMin(&minKey[rb], key);
      }
    }
    __syncthreads();
    if (tid < 64) {
      u64 k0 = minKey[lane], k1 = minKey[64 + lane];
      unsigned mi0 = (k0 != ~0ull) ? (unsigned)(k0 & 0xffffffffull) : 0xFFFFFFFFu;
      unsigned mi1 = (k1 != ~0ull) ? (unsigned)(k1 & 0xffffffffull) : 0xFFFFFFFFu;
      u64 ev0 = (mi0 != 0xFFFFFFFFu) ? slist2[mi0] : 0ull;
      u64 ev1 = (mi1 != 0xFFFFFFFFu) ? slist2[mi1] : 0ull;
      int a0 = (int)(ev0 & 0xffull), b0 = (int)((ev0 >> 8) & 0xffull);
      int a1 = (int)(ev1 & 0xffull), b1 = (int)((ev1 >> 8) & 0xffull);
      int raA = sel2(comp0, comp1, a0), rbA = sel2(comp0, comp1, b0);
      int raB = sel2(comp0, comp1, a1), rbB = sel2(comp0, comp1, b1);
      int parA0 = (mi0 != 0xFFFFFFFFu) ? ((raA == lane) ? rbA : raA) : lane;
      int parA1 = (mi1 != 0xFFFFFFFFu) ? ((raB == 64 + lane) ? rbB : raB) : (64 + lane);
      // 2-cycle resolve (distinct (w,idx) keys => only 2-cycles possible)
      int pp0 = sel2(parA0, parA1, parA0);
      int pp1 = sel2(parA0, parA1, parA1);
      int par0 = (pp0 == lane && lane < parA0) ? lane : parA0;
      int par1 = (pp1 == (64 + lane) && (64 + lane) < parA1) ? (64 + lane) : parA1;
      // collect MST edges (hooker contributes its edge)
      bool h0 = (par0 != lane);
      bool h1 = (par1 != (64 + lane));
      u64 mlo = __ballot(h0);
      int cnt0 = __popcll(mlo);
      int pos0 = nmst + __popcll(mlo & ((1ull << lane) - 1ull));
      if (h0 && pos0 < 128) mstlist[pos0] = ev0;
      u64 mhi = __ballot(h1);
      int pos1 = nmst + cnt0 + __popcll(mhi & ((1ull << lane) - 1ull));
      if (h1 && pos1 < 128) mstlist[pos1] = ev1;
      int tot = cnt0 + __popcll(mhi);
      nmst += tot;
      if (lane == 0 && tot > 0) c_hook = 1;
      // compress par, then update comp
      for (int j = 0; j < 7; ++j) {
        int n0 = sel2(par0, par1, par0);
        int n1 = sel2(par0, par1, par1);
        bool chp = (n0 != par0) || (n1 != par1);
        par0 = n0; par1 = n1;
        if (__ballot(chp) == 0ull) break;
      }
      comp0 = sel2(par0, par1, comp0);
      comp1 = sel2(par0, par1, comp1);
    }
    __syncthreads();
    if (c_hook == 0) break;
  }

  // ---- wave0: in-register sort of <=128 MST edges + serial readlane Kruskal ----
  if (tid < 64) {
    u64 e0 = mstlist[lane], e1 = mstlist[64 + lane];
    ALL2(1,2)
    ALL2(2,4) ALL2(1,4)
    ALL2(4,8) ALL2(2,8) ALL2(1,8)
    ALL2(8,16) ALL2(4,16) ALL2(2,16) ALL2(1,16)
    ALL2(16,32) ALL2(8,32) ALL2(4,32) ALL2(2,32) ALL2(1,32)
    ALL2(32,64) ALL2(16,64) ALL2(8,64) ALL2(4,64) ALL2(2,64) ALL2(1,64)
    CXR(0,1,128)
    ALL2(32,128) ALL2(16,128) ALL2(8,128) ALL2(4,128) ALL2(2,128) ALL2(1,128)

    int p0 = lane, p1 = 64 + lane;
    float m0 = smu[lane], m1 = smu[64 + lane];
    int r0 = sminv[lane], r1 = sminv[64 + lane];
    int np = 0;
    for (int s = 0; s < nmst; ++s) {
      u64 ev = (s < 64) ? rdl64(e0, s) : rdl64(e1, s - 64);
      int a = (int)(ev & 0xffull), bb2 = (int)((ev >> 8) & 0xffull);
      unsigned wb = (unsigned)(ev >> 32);
      int ia = a & 63, ib = bb2 & 63;
      int pa = (a < 64) ? rdl(p0, ia) : rdl(p1, ia);
      int pb = (bb2 < 64) ? rdl(p0, ib) : rdl(p1, ib);
      if (pa == pb) continue;  // MST edges never cycle; insurance
      float ma = (a < 64) ? rdlf(m0, ia) : rdlf(m1, ia);
      float mb = (bb2 < 64) ? rdlf(m0, ib) : rdlf(m1, ib);
      int ra = (a < 64) ? rdl(r0, ia) : rdl(r1, ia);
      int rb = (bb2 < 64) ? rdl(r0, ib) : rdl(r1, ib);
      bool aeld = (ma < mb) || (ma == mb && ra <= rb);
      int eld = aeld ? pa : pb, yng = aeld ? pb : pa;
      float m_e = aeld ? ma : mb; int r_e = aeld ? ra : rb;
      float byoung = aeld ? mb : ma;
      bool g0 = (p0 == yng), g1 = (p1 == yng);
      p0 = g0 ? eld : p0; m0 = g0 ? m_e : m0; r0 = g0 ? r_e : r0;
      p1 = g1 ? eld : p1; m1 = g1 ? m_e : m1; r1 = g1 ? r_e : r1;
      if (lane == 0 && np < PAIRCAP - 1) spairs[np] = make_float2(byoung, __uint_as_float(wb));
      np++;
    }
    if (np > PAIRCAP - 1) np = PAIRCAP - 1;
    if (lane == 0) {
      spairs[np] = make_float2(__uint_as_float(fminb), __uint_as_float(fmaxb));  // essential pair
      c_np = np + 1;
    }
  }
  __syncthreads();

  // landscape (top-2 triangles at 25 t's)
  int totp = c_np;
  if (tid < 25) {
    float tv = 1.875f * (float)tid;
    float top1 = 0.f, top2 = 0.f;
    for (int i = 0; i < totp; ++i) {
      float2 p = spairs[i];
      float tri = fminf(tv - p.x, p.y - tv);
      tri = fmaxf(tri, 0.f);
      if (tri > top1) { top2 = top1; top1 = tri; }
      else if (tri > top2) top2 = tri;
    }
    sland[tid] = top1;
    sland[25 + tid] = top2;
  }
  __syncthreads();

  // x = land @ Wg.T + bg
  if (tid < 50) {
    float acc = sbg[tid];
    for (int k = 0; k < 50; ++k) acc += sland[k] * sWg[tid * 50 + k];
    sx[tid] = acc;
  }
  __syncthreads();

  // outputs
  if (tid < 50) atomicAdd(&out[20 + tid], fabsf(sx[tid]));
  if (tid >= 64 && tid < 74) {
    int c = tid - 64;
    float acc = sbfc[c];
    for (int o = 0; o < 50; ++o) acc += fmaxf(sx[o], 0.f) * sWfc[c * 50 + o];
    out[b * 10 + c] = acc;
  }
}

extern "C" void kernel_launch(void* const* d_in, const int* in_sizes, int n_in,
                              void* d_out, int out_size, void* d_ws, size_t ws_size,
                              hipStream_t stream) {
  (void)in_sizes; (void)n_in; (void)out_size; (void)ws_size;
  const float* input = (const float*)d_in[0];
  const float* Wg  = (const float*)d_in[1];
  const float* bg  = (const float*)d_in[2];
  const float* Wfc = (const float*)d_in[3];
  const float* bfc = (const float*)d_in[4];
  float* out = (float*)d_out;

  float* f_ws = (float*)d_ws;  // 2*4096 f32

  dtm_kernel<<<dim3(256, 2), 1024, 0, stream>>>(input, f_ws, out);
  ph_fused<<<dim3(2), 1024, 0, stream>>>(f_ws, Wg, bg, Wfc, bfc, out);
}

// Round 17
// 58.292 us; speedup vs baseline: 1.5391x; 1.0782x over previous
//
#include <hip/hip_runtime.h>

#define NPTS 4096
#define NEDGE 8064
#define M0f 0.05f
#define KMAXD2 7938
#define IDCAP 90          // basin-id clamp; triangular pair table needs IDCAP*(IDCAP-1)/2 <= 4096
#define SORTCAP 512
#define PAIRCAP 160
#define MSTCAP 256        // >= 2*(IDCAP-1) duplicate-inclusive Boruvka collection bound

typedef unsigned long long u64;

__device__ inline float waveSum(float x) {
  for (int m = 32; m >= 1; m >>= 1) x += __shfl_xor(x, m);
  return x;
}

__device__ inline int isqrt_i(int x) {  // exact floor sqrt for 0 <= x < 2^20
  int r = (int)sqrtf((float)x);
  if ((r + 1) * (r + 1) <= x) r++;
  else if (r * r > x) r--;
  return r;
}

// uniform-index readlane helpers
__device__ inline int rdl(int v, int l) { return __builtin_amdgcn_readlane(v, l); }
__device__ inline u64 rdl64(u64 x, int l) {
  unsigned lo = (unsigned)__builtin_amdgcn_readlane((int)(unsigned)(x & 0xffffffffull), l);
  unsigned hi = (unsigned)__builtin_amdgcn_readlane((int)(unsigned)(x >> 32), l);
  return ((u64)hi << 32) | (u64)lo;
}
// dynamic select from a 128-entry register file split across wave (v0: ids 0-63, v1: 64-127)
__device__ inline int sel2(int v0, int v1, int idx) {
  int x0 = __shfl(v0, idx & 63);
  int x1 = __shfl(v1, idx & 63);
  return (idx < 64) ? x0 : x1;
}
__device__ inline u64 shfl_xor64(u64 x, int m) {
  int lo = __shfl_xor((int)(unsigned)(x & 0xffffffffull), m);
  int hi = __shfl_xor((int)(unsigned)(x >> 32), m);
  return ((u64)(unsigned)hi << 32) | (u64)(unsigned)lo;
}

// in-wave bitonic compare-exchange (element i = R*64 + lane), N=256 over 4 regs
#define CXL(R, J, K) { \
  u64 vo = shfl_xor64(e##R, J); \
  bool up = (((((R) * 64) & (K)) | (lane & (K))) == 0); \
  bool lower = ((lane & (J)) == 0); \
  bool kmin = (lower == up); \
  u64 mn = (e##R < vo) ? e##R : vo; \
  u64 mx = (e##R < vo) ? vo : e##R; \
  e##R = kmin ? mn : mx; }
#define ALL4(J, K) CXL(0,J,K) CXL(1,J,K) CXL(2,J,K) CXL(3,J,K)
#define CXR(RA, RB, K) { \
  const bool up = ((((RA) * 64) & (K)) == 0); \
  u64 va = e##RA, vb = e##RB; \
  u64 mn = (va < vb) ? va : vb; \
  u64 mx = (va < vb) ? vb : va; \
  e##RA = up ? mn : mx; e##RB = up ? mx : mn; }

// ---------------- Kernel 1: DTM (hybrid interpolation search) + out-zero ----------------
__global__ __launch_bounds__(1024) void dtm_kernel(const float* __restrict__ win,
                                                   float* __restrict__ fout,
                                                   float* __restrict__ out) {
  __shared__ float P0[64][65];
  __shared__ float P1[64][65];
  __shared__ float P2[64][65];
  int b = blockIdx.y;
  const float* w = win + b * NPTS;
  int tid = threadIdx.x, lane = tid & 63, wv = tid >> 6;

  if (blockIdx.x == 0 && blockIdx.y == 0 && tid < 50) out[20 + tid] = 0.f;  // signal accum base

  for (int rr = 0; rr < 4; ++rr) {
    int r = (wv << 2) | rr;
    float x0 = w[(r << 6) | lane];
    float fl = (float)lane;
    float x1 = x0 * fl, x2 = x1 * fl;
    for (int d = 1; d < 64; d <<= 1) {
      float t0 = __shfl_up(x0, d);
      float t1 = __shfl_up(x1, d);
      float t2 = __shfl_up(x2, d);
      if (lane >= d) { x0 += t0; x1 += t1; x2 += t2; }
    }
    P0[r][lane] = x0; P1[r][lane] = x1; P2[r][lane] = x2;
  }
  __syncthreads();

  float sumw = waveSum(P0[lane][63]);
  float thr = M0f * sumw;

  int q = blockIdx.x * 16 + wv;
  int qi = q >> 6, qj = q & 63;
  int di = qi - lane;
  int disq = di * di;

  auto evalF = [&](int K) -> float {
    float s0 = 0.f;
    int rem = K - disq;
    if (rem >= 0) {
      int r = isqrt_i(rem);
      int l0 = qj - r; l0 = l0 < 0 ? 0 : l0;
      int h0 = qj + r; h0 = h0 > 63 ? 63 : h0;
      s0 = P0[lane][h0] - (l0 > 0 ? P0[lane][l0 - 1] : 0.f);
    }
    return waveSum(s0);
  };

  // hybrid interpolation/bisection: invariant Flo < thr <= Fhi; bisect every 2nd probe
  // guarantees <= 2*log2 bound; interpolation (F near-linear in K) typically ~5-7 probes.
  int lo = -1, hi = KMAXD2;
  float Flo = 0.f, Fhi = sumw;
  int itc = 0;
  while (hi - lo > 1 && itc < 40) {
    int mid;
    if (itc & 1) {
      mid = (lo + hi) >> 1;
    } else {
      float t = (thr - Flo) / fmaxf(Fhi - Flo, 1e-30f);
      mid = lo + (int)(t * (float)(hi - lo));
      mid = mid < lo + 1 ? lo + 1 : (mid > hi - 1 ? hi - 1 : mid);
    }
    float F = evalF(mid);
    if (F >= thr) { hi = mid; Fhi = F; } else { lo = mid; Flo = F; }
    ++itc;
  }
  int kstar = hi;
  float Fm = Flo;

  float g = 0.f;
  {
    int rem = (kstar - 1) - disq;
    if (rem >= 0) {
      int r = isqrt_i(rem);
      int l0 = qj - r; l0 = l0 < 0 ? 0 : l0;
      int h0 = qj + r; h0 = h0 > 63 ? 63 : h0;
      float S0 = P0[lane][h0] - (l0 > 0 ? P0[lane][l0 - 1] : 0.f);
      float S1 = P1[lane][h0] - (l0 > 0 ? P1[lane][l0 - 1] : 0.f);
      float S2 = P2[lane][h0] - (l0 > 0 ? P2[lane][l0 - 1] : 0.f);
      float fq = (float)qj;
      g = (float)disq * S0 + fq * fq * S0 - 2.f * fq * S1 + S2;
    }
  }
  float G = waveSum(g);
  float val = (G + (thr - Fm) * (float)kstar) / thr;
  val = val < 0.f ? 0.f : val;
  float res = (224.f / 63.f) * sqrtf(val);
  if (lane == 0) fout[b * NPTS + q] = res;
}

// ---------------- Kernel 2: fused PH0 (Boruvka) + landscape + MLP ----------------
__global__ __launch_bounds__(1024) void ph_fused(const float* __restrict__ fin,
                                                 const float* __restrict__ Wg,
                                                 const float* __restrict__ bg,
                                                 const float* __restrict__ Wfc,
                                                 const float* __restrict__ bfc,
                                                 float* __restrict__ out) {
  __shared__ __align__(16) float sf[NPTS];
  __shared__ __align__(16) int srep[NPTS];    // aliased later: unsigned ptable[4096]
  __shared__ __align__(16) int sbasin[NPTS];  // aliased later: u64 slist2[SORTCAP]
  __shared__ float smu[128];
  __shared__ int sminv[128];
  __shared__ float2 spairs[PAIRCAP];
  __shared__ float sland[50];
  __shared__ float sx[50];
  __shared__ __align__(16) float sWg[2500];
  __shared__ float sbg[50];
  __shared__ __align__(16) float sWfc[500];
  __shared__ float sbfc[10];
  __shared__ int comparr[128];
  __shared__ u64 minKey[128];
  __shared__ u64 mstlist[MSTCAP];
  __shared__ int c_m, c_np, c_hook, c_chg;
  __shared__ unsigned fminb, fmaxb;
  __shared__ int c_l2;

  int b = blockIdx.x;
  int tid = threadIdx.x;
  int lane = tid & 63;
  if (tid == 0) { c_m = 0; c_l2 = 0; c_np = 0; c_chg = 0; fminb = 0x7f800000u; fmaxb = 0u; }
  if (tid < 128) { smu[tid] = 3.0e38f; sminv[tid] = tid; }
  if (tid < MSTCAP) mstlist[tid] = ~0ull;

  // weight prefetch, vectorized (consumed at the end)
  if (tid < 625) ((float4*)sWg)[tid] = ((const float4*)Wg)[tid];
  if (tid < 125) ((float4*)sWfc)[tid] = ((const float4*)Wfc)[tid];
  if (tid < 50) sbg[tid] = bg[tid];
  if (tid >= 64 && tid < 74) sbfc[tid - 64] = bfc[tid - 64];

  // load f (float4), per-wave min/max
  {
    float4 v4 = ((const float4*)(fin + b * NPTS))[tid];
    ((float4*)sf)[tid] = v4;
    float lmin = fminf(fminf(v4.x, v4.y), fminf(v4.z, v4.w));
    float lmax = fmaxf(fmaxf(v4.x, v4.y), fmaxf(v4.z, v4.w));
    for (int m = 32; m >= 1; m >>= 1) {
      lmin = fminf(lmin, __shfl_xor(lmin, m));
      lmax = fmaxf(lmax, __shfl_xor(lmax, m));
    }
    if (lane == 0) {
      atomicMin(&fminb, __float_as_uint(lmin));
      atomicMax(&fmaxb, __float_as_uint(lmax));
    }
  }
  __syncthreads();

  // steepest-descent pointers
  int preg[4];
#pragma unroll 4
  for (int s = 0; s < 4; ++s) {
    int v = tid + s * 1024;
    int vi = v >> 6, vj = v & 63;
    float bf = sf[v]; int bi = v;
    if (vj > 0)  { float fn = sf[v - 1];  int n = v - 1;  if (fn < bf || (fn == bf && n < bi)) { bf = fn; bi = n; } }
    if (vj < 63) { float fn = sf[v + 1];  int n = v + 1;  if (fn < bf || (fn == bf && n < bi)) { bf = fn; bi = n; } }
    if (vi > 0)  { float fn = sf[v - 64]; int n = v - 64; if (fn < bf || (fn == bf && n < bi)) { bf = fn; bi = n; } }
    if (vi < 63) { float fn = sf[v + 64]; int n = v + 64; if (fn < bf || (fn == bf && n < bi)) { bf = fn; bi = n; } }
    srep[v] = bi;
    preg[s] = bi;
  }
  __syncthreads();

  // pointer jumping, double-hop, early-exit via round-stamped flag (benign same-value races)
  for (int it = 0; it < 8; ++it) {
    bool ch = false;
#pragma unroll 4
    for (int s = 0; s < 4; ++s) {
      int x = srep[preg[s]];
      x = srep[x];
      ch |= (x != preg[s]);
      srep[tid + s * 1024] = x;
      preg[s] = x;
    }
    u64 bl = __ballot(ch);
    if (lane == 0 && bl != 0ull) c_chg = it + 1;
    __syncthreads();
    if (c_chg != it + 1) break;   // nobody changed this round -> all at roots
  }

  // compact basin ids at minima
  for (int v = tid; v < NPTS; v += 1024) {
    if (srep[v] == v) {
      int id = atomicAdd(&c_m, 1);
      if (id < IDCAP) { sbasin[v] = id; smu[id] = sf[v]; sminv[id] = v; }
      else sbasin[v] = IDCAP - 1;
    }
  }
  __syncthreads();
  for (int v = tid; v < NPTS; v += 1024) {
    if (srep[v] != v) sbasin[v] = sbasin[srep[v]];
  }
  __syncthreads();   // srep dead

  // dedup via triangular pair table (aliases srep)
  unsigned* ptable = (unsigned*)srep;
  for (int i = tid; i < 4096; i += 1024) ptable[i] = 0xFFFFFFFFu;
  __syncthreads();
  for (int e = tid; e < NEDGE; e += 1024) {
    int u, v2;
    if (e < 4032) { int i = e / 63; int j = e - i * 63; u = (i << 6) | j; v2 = u + 1; }
    else          { int e2 = e - 4032; u = e2; v2 = u + 64; }
    int bu = sbasin[u], bv = sbasin[v2];
    if (bu != bv) {
      float wgt = fmaxf(sf[u], sf[v2]);
      int a = bu < bv ? bu : bv, bb2 = bu < bv ? bv : bu;
      int t = (bb2 * (bb2 - 1)) / 2 + a;
      atomicMin(&ptable[t], __float_as_uint(wgt));
    }
  }
  __syncthreads();   // sbasin dead

  // compact table -> slist2 (aliases sbasin): (w<<32) | (b<<8) | a
  u64* slist2 = (u64*)sbasin;
  for (int t = tid; t < 4096; t += 1024) {
    unsigned wv2 = ptable[t];
    if (wv2 != 0xFFFFFFFFu) {
      int bb2 = (int)((1.0f + sqrtf(1.0f + 8.0f * (float)t)) * 0.5f);
      while (bb2 > 1 && (bb2 * (bb2 - 1)) / 2 > t) bb2--;
      while (((bb2 + 1) * bb2) / 2 <= t) bb2++;
      int aa = t - (bb2 * (bb2 - 1)) / 2;
      int slot = atomicAdd(&c_l2, 1);
      if (slot < SORTCAP) slist2[slot] = ((u64)wv2 << 32) | (unsigned)((bb2 << 8) | aa);
    }
  }
  __syncthreads();
  int n2 = c_l2; if (n2 > SORTCAP) n2 = SORTCAP;

  // ---- Boruvka contraction, single-pass min-edge via u64 atomicMin on (w, edge_idx) ----
  int comp0 = lane, comp1 = 64 + lane;   // meaningful in wave0 only
  int nmst = 0;
  for (int round = 0; round < 7; ++round) {
    if (tid < 64) {
      comparr[lane] = comp0; comparr[64 + lane] = comp1;
      if (lane == 0) c_hook = 0;
    }
    if (tid < 128) minKey[tid] = ~0ull;
    __syncthreads();
    for (int e = tid; e < n2; e += 1024) {
      u64 ev = slist2[e];
      int a = (int)(ev & 0xffull), bb2 = (int)((ev >> 8) & 0xffull);
      int ra = comparr[a], rb = comparr[bb2];
      if (ra != rb) {
        u64 key = (ev & 0xFFFFFFFF00000000ull) | (u64)(unsigned)e;  // (w, idx): total order
        atomicMin(&minKey[ra], key);
        atomicMin(&minKey[rb], key);
      }
    }
    __syncthreads();
    if (tid < 64) {
      u64 k0 = minKey[lane], k1 = minKey[64 + lane];
      unsigned mi0 = (k0 != ~0ull) ? (unsigned)(k0 & 0xffffffffull) : 0xFFFFFFFFu;
      unsigned mi1 = (k1 != ~0ull) ? (unsigned)(k1 & 0xffffffffull) : 0xFFFFFFFFu;
      u64 ev0 = (mi0 != 0xFFFFFFFFu) ? slist2[mi0] : 0ull;
      u64 ev1 = (mi1 != 0xFFFFFFFFu) ? slist2[mi1] : 0ull;
      int a0 = (int)(ev0 & 0xffull), b0 = (int)((ev0 >> 8) & 0xffull);
      int a1 = (int)(ev1 & 0xffull), b1 = (int)((ev1 >> 8) & 0xffull);
      int raA = sel2(comp0, comp1, a0), rbA = sel2(comp0, comp1, b0);
      int raB = sel2(comp0, comp1, a1), rbB = sel2(comp0, comp1, b1);
      int parA0 = (mi0 != 0xFFFFFFFFu) ? ((raA == lane) ? rbA : raA) : lane;
      int parA1 = (mi1 != 0xFFFFFFFFu) ? ((raB == 64 + lane) ? rbB : raB) : (64 + lane);
      // 2-cycle resolve (distinct (w,idx) keys => only 2-cycles possible)
      int pp0 = sel2(parA0, parA1, parA0);
      int pp1 = sel2(parA0, parA1, parA1);
      int par0 = (pp0 == lane && lane < parA0) ? lane : parA0;
      int par1 = (pp1 == (64 + lane) && (64 + lane) < parA1) ? (64 + lane) : parA1;
      // collect MST edges (hooker contributes its edge; mutual-min edges appear twice -> Kruskal skips)
      bool h0 = (par0 != lane);
      bool h1 = (par1 != (64 + lane));
      u64 mlo = __ballot(h0);
      int cnt0 = __popcll(mlo);
      int pos0 = nmst + __popcll(mlo & ((1ull << lane) - 1ull));
      if (h0 && pos0 < MSTCAP) mstlist[pos0] = ev0;
      u64 mhi = __ballot(h1);
      int pos1 = nmst + cnt0 + __popcll(mhi & ((1ull << lane) - 1ull));
      if (h1 && pos1 < MSTCAP) mstlist[pos1] = ev1;
      int tot = cnt0 + __popcll(mhi);
      nmst += tot;
      if (lane == 0 && tot > 0) c_hook = 1;
      // compress par, then update comp
      for (int j = 0; j < 7; ++j) {
        int n0 = sel2(par0, par1, par0);
        int n1 = sel2(par0, par1, par1);
        bool chp = (n0 != par0) || (n1 != par1);
        par0 = n0; par1 = n1;
        if (__ballot(chp) == 0ull) break;
      }
      comp0 = sel2(par0, par1, comp0);
      comp1 = sel2(par0, par1, comp1);
    }
    __syncthreads();
    if (c_hook == 0) break;
  }
  if (nmst > MSTCAP) nmst = MSTCAP;

  // ---- wave0: in-register sort of <=256 collected edges + packed-state readlane Kruskal ----
  if (tid < 64) {
    u64 e0 = mstlist[lane], e1 = mstlist[64 + lane], e2 = mstlist[128 + lane], e3 = mstlist[192 + lane];
    // bitonic N=256 over 4 regs (element i = R*64+lane), ascending; zero barriers
    ALL4(1,2)
    ALL4(2,4) ALL4(1,4)
    ALL4(4,8) ALL4(2,8) ALL4(1,8)
    ALL4(8,16) ALL4(4,16) ALL4(2,16) ALL4(1,16)
    ALL4(16,32) ALL4(8,32) ALL4(4,32) ALL4(2,32) ALL4(1,32)
    ALL4(32,64) ALL4(16,64) ALL4(8,64) ALL4(4,64) ALL4(2,64) ALL4(1,64)
    CXR(0,1,128) CXR(2,3,128)
    ALL4(32,128) ALL4(16,128) ALL4(8,128) ALL4(4,128) ALL4(2,128) ALL4(1,128)
    CXR(0,2,256) CXR(1,3,256)
    CXR(0,1,256) CXR(2,3,256)
    ALL4(32,256) ALL4(16,256) ALL4(8,256) ALL4(4,256) ALL4(2,256) ALL4(1,256)

    // packed union-find state per id: (mu_bits<<32) | (rv<<13) | p
    // invariant: each id's state carries its ROOT's (mu, rv) and root id p.
    // elder test: (stA>>13) < (stB>>13)  == (muA<muB) || (muA==muB && rvA<rvB); rv unique per root.
    u64 st0 = ((u64)__float_as_uint(smu[lane]) << 32) | ((u64)(unsigned)sminv[lane] << 13) | (unsigned)lane;
    u64 st1 = ((u64)__float_as_uint(smu[64 + lane]) << 32) | ((u64)(unsigned)sminv[64 + lane] << 13) | (unsigned)(64 + lane);
    int np = 0;
#define KBLK(R, BASE) \
    for (int s = 0; s < 64; ++s) { \
      if (BASE + s >= nmst) break; \
      u64 ev = rdl64(e##R, s); \
      int a = (int)(ev & 0xffull), bb2 = (int)((ev >> 8) & 0xffull); \
      int ia = a & 63, ib = bb2 & 63; \
      u64 stA = (a < 64) ? rdl64(st0, ia) : rdl64(st1, ia); \
      u64 stB = (bb2 < 64) ? rdl64(st0, ib) : rdl64(st1, ib); \
      int pa = (int)(stA & 127ull), pb = (int)(stB & 127ull); \
      if (pa == pb) continue; \
      bool aeld = (stA >> 13) < (stB >> 13); \
      u64 stE = aeld ? stA : stB; \
      u64 stY = aeld ? stB : stA; \
      unsigned yng = (unsigned)(stY & 127ull); \
      float byoung = __uint_as_float((unsigned)(stY >> 32)); \
      bool g0 = ((unsigned)(st0 & 127ull) == yng); st0 = g0 ? stE : st0; \
      bool g1 = ((unsigned)(st1 & 127ull) == yng); st1 = g1 ? stE : st1; \
      if (lane == 0 && np < PAIRCAP - 1) spairs[np] = make_float2(byoung, __uint_as_float((unsigned)(ev >> 32))); \
      np++; \
    }
    KBLK(0, 0) KBLK(1, 64) KBLK(2, 128) KBLK(3, 192)
#undef KBLK
    if (np > PAIRCAP - 1) np = PAIRCAP - 1;
    if (lane == 0) {
      spairs[np] = make_float2(__uint_as_float(fminb), __uint_as_float(fmaxb));  // essential pair
      c_np = np + 1;
    }
  }
  __syncthreads();

  // landscape (top-2 triangles at 25 t's)
  int totp = c_np;
  if (tid < 25) {
    float tv = 1.875f * (float)tid;
    float top1 = 0.f, top2 = 0.f;
    for (int i = 0; i < totp; ++i) {
      float2 p = spairs[i];
      float tri = fminf(tv - p.x, p.y - tv);
      tri = fmaxf(tri, 0.f);
      if (tri > top1) { top2 = top1; top1 = tri; }
      else if (tri > top2) top2 = tri;
    }
    sland[tid] = top1;
    sland[25 + tid] = top2;
  }
  __syncthreads();

  // x = land @ Wg.T + bg
  if (tid < 50) {
    float acc = sbg[tid];
    for (int k = 0; k < 50; ++k) acc += sland[k] * sWg[tid * 50 + k];
    sx[tid] = acc;
  }
  __syncthreads();

  // outputs
  if (tid < 50) atomicAdd(&out[20 + tid], fabsf(sx[tid]));
  if (tid >= 64 && tid < 74) {
    int c = tid - 64;
    float acc = sbfc[c];
    for (int o = 0; o < 50; ++o) acc += fmaxf(sx[o], 0.f) * sWfc[c * 50 + o];
    out[b * 10 + c] = acc;
  }
}

extern "C" void kernel_launch(void* const* d_in, const int* in_sizes, int n_in,
                              void* d_out, int out_size, void* d_ws, size_t ws_size,
                              hipStream_t stream) {
  (void)in_sizes; (void)n_in; (void)out_size; (void)ws_size;
  const float* input = (const float*)d_in[0];
  const float* Wg  = (const float*)d_in[1];
  const float* bg  = (const float*)d_in[2];
  const float* Wfc = (const float*)d_in[3];
  const float* bfc = (const float*)d_in[4];
  float* out = (float*)d_out;

  float* f_ws = (float*)d_ws;  // 2*4096 f32

  dtm_kernel<<<dim3(256, 2), 1024, 0, stream>>>(input, f_ws, out);
  ph_fused<<<dim3(2), 1024, 0, stream>>>(f_ws, Wg, bg, Wfc, bfc, out);
}

// Round 18
// 55.564 us; speedup vs baseline: 1.6147x; 1.0491x over previous
//
#include <hip/hip_runtime.h>

#define NPTS 4096
#define NEDGE 8064
#define M0f 0.05f
#define KMAXD2 7938
#define IDCAP 90          // basin-id clamp; triangular pair table needs IDCAP*(IDCAP-1)/2 <= 4096
#define SORTCAP 512
#define PAIRCAP 160
#define MSTCAP 128        // collected edges = #merges <= IDCAP-1 = 89 (distinct; mutual-min collects once)

typedef unsigned long long u64;

__device__ inline float waveSum(float x) {
  for (int m = 32; m >= 1; m >>= 1) x += __shfl_xor(x, m);
  return x;
}

__device__ inline int isqrt_i(int x) {  // exact floor sqrt for 0 <= x < 2^20
  int r = (int)sqrtf((float)x);
  if ((r + 1) * (r + 1) <= x) r++;
  else if (r * r > x) r--;
  return r;
}

// uniform-index readlane helpers
__device__ inline int rdl(int v, int l) { return __builtin_amdgcn_readlane(v, l); }
__device__ inline u64 rdl64(u64 x, int l) {
  unsigned lo = (unsigned)__builtin_amdgcn_readlane((int)(unsigned)(x & 0xffffffffull), l);
  unsigned hi = (unsigned)__builtin_amdgcn_readlane((int)(unsigned)(x >> 32), l);
  return ((u64)hi << 32) | (u64)lo;
}
// dynamic select from a 128-entry register file split across wave (v0: ids 0-63, v1: 64-127)
__device__ inline int sel2(int v0, int v1, int idx) {
  int x0 = __shfl(v0, idx & 63);
  int x1 = __shfl(v1, idx & 63);
  return (idx < 64) ? x0 : x1;
}
__device__ inline u64 shfl_xor64(u64 x, int m) {
  int lo = __shfl_xor((int)(unsigned)(x & 0xffffffffull), m);
  int hi = __shfl_xor((int)(unsigned)(x >> 32), m);
  return ((u64)(unsigned)hi << 32) | (u64)(unsigned)lo;
}

// in-wave bitonic compare-exchange (element i = R*64 + lane), N=128 over 2 regs
#define CXL(R, J, K) { \
  u64 vo = shfl_xor64(e##R, J); \
  bool up = (((((R) * 64) & (K)) | (lane & (K))) == 0); \
  bool lower = ((lane & (J)) == 0); \
  bool kmin = (lower == up); \
  u64 mn = (e##R < vo) ? e##R : vo; \
  u64 mx = (e##R < vo) ? vo : e##R; \
  e##R = kmin ? mn : mx; }
#define ALL2(J, K) CXL(0,J,K) CXL(1,J,K)
#define CXR(RA, RB, K) { \
  const bool up = ((((RA) * 64) & (K)) == 0); \
  u64 va = e##RA, vb = e##RB; \
  u64 mn = (va < vb) ? va : vb; \
  u64 mx = (va < vb) ? vb : va; \
  e##RA = up ? mn : mx; e##RB = up ? mx : mn; }

// ---------------- Kernel 1: DTM (hybrid interpolation search) + out-zero ----------------
__global__ __launch_bounds__(1024) void dtm_kernel(const float* __restrict__ win,
                                                   float* __restrict__ fout,
                                                   float* __restrict__ out) {
  __shared__ float P0[64][65];
  __shared__ float P1[64][65];
  __shared__ float P2[64][65];
  int b = blockIdx.y;
  const float* w = win + b * NPTS;
  int tid = threadIdx.x, lane = tid & 63, wv = tid >> 6;

  if (blockIdx.x == 0 && blockIdx.y == 0 && tid < 50) out[20 + tid] = 0.f;  // signal accum base

  for (int rr = 0; rr < 4; ++rr) {
    int r = (wv << 2) | rr;
    float x0 = w[(r << 6) | lane];
    float fl = (float)lane;
    float x1 = x0 * fl, x2 = x1 * fl;
    for (int d = 1; d < 64; d <<= 1) {
      float t0 = __shfl_up(x0, d);
      float t1 = __shfl_up(x1, d);
      float t2 = __shfl_up(x2, d);
      if (lane >= d) { x0 += t0; x1 += t1; x2 += t2; }
    }
    P0[r][lane] = x0; P1[r][lane] = x1; P2[r][lane] = x2;
  }
  __syncthreads();

  float sumw = waveSum(P0[lane][63]);
  float thr = M0f * sumw;

  int q = blockIdx.x * 16 + wv;
  int qi = q >> 6, qj = q & 63;
  int di = qi - lane;
  int disq = di * di;

  auto evalF = [&](int K) -> float {
    float s0 = 0.f;
    int rem = K - disq;
    if (rem >= 0) {
      int r = isqrt_i(rem);
      int l0 = qj - r; l0 = l0 < 0 ? 0 : l0;
      int h0 = qj + r; h0 = h0 > 63 ? 63 : h0;
      s0 = P0[lane][h0] - (l0 > 0 ? P0[lane][l0 - 1] : 0.f);
    }
    return waveSum(s0);
  };

  // hybrid interpolation/bisection: invariant Flo < thr <= Fhi; bisect every 2nd probe
  int lo = -1, hi = KMAXD2;
  float Flo = 0.f, Fhi = sumw;
  int itc = 0;
  while (hi - lo > 1 && itc < 40) {
    int mid;
    if (itc & 1) {
      mid = (lo + hi) >> 1;
    } else {
      float t = (thr - Flo) / fmaxf(Fhi - Flo, 1e-30f);
      mid = lo + (int)(t * (float)(hi - lo));
      mid = mid < lo + 1 ? lo + 1 : (mid > hi - 1 ? hi - 1 : mid);
    }
    float F = evalF(mid);
    if (F >= thr) { hi = mid; Fhi = F; } else { lo = mid; Flo = F; }
    ++itc;
  }
  int kstar = hi;
  float Fm = Flo;

  float g = 0.f;
  {
    int rem = (kstar - 1) - disq;
    if (rem >= 0) {
      int r = isqrt_i(rem);
      int l0 = qj - r; l0 = l0 < 0 ? 0 : l0;
      int h0 = qj + r; h0 = h0 > 63 ? 63 : h0;
      float S0 = P0[lane][h0] - (l0 > 0 ? P0[lane][l0 - 1] : 0.f);
      float S1 = P1[lane][h0] - (l0 > 0 ? P1[lane][l0 - 1] : 0.f);
      float S2 = P2[lane][h0] - (l0 > 0 ? P2[lane][l0 - 1] : 0.f);
      float fq = (float)qj;
      g = (float)disq * S0 + fq * fq * S0 - 2.f * fq * S1 + S2;
    }
  }
  float G = waveSum(g);
  float val = (G + (thr - Fm) * (float)kstar) / thr;
  val = val < 0.f ? 0.f : val;
  float res = (224.f / 63.f) * sqrtf(val);
  if (lane == 0) fout[b * NPTS + q] = res;
}

// ---------------- Kernel 2: fused PH0 (Boruvka) + landscape + MLP ----------------
__global__ __launch_bounds__(1024) void ph_fused(const float* __restrict__ fin,
                                                 const float* __restrict__ Wg,
                                                 const float* __restrict__ bg,
                                                 const float* __restrict__ Wfc,
                                                 const float* __restrict__ bfc,
                                                 float* __restrict__ out) {
  __shared__ __align__(16) float sf[NPTS];
  __shared__ __align__(16) int srep[NPTS];    // aliased later: unsigned ptable[4096]
  __shared__ __align__(16) int sbasin[NPTS];  // aliased later: u64 slist2[SORTCAP]
  __shared__ float smu[128];
  __shared__ int sminv[128];
  __shared__ float2 spairs[PAIRCAP];
  __shared__ float sland[50];
  __shared__ float sx[50];
  __shared__ __align__(16) float sWg[2500];
  __shared__ float sbg[50];
  __shared__ __align__(16) float sWfc[500];
  __shared__ float sbfc[10];
  __shared__ int comparr[128];
  __shared__ u64 minKey[128];
  __shared__ u64 mstlist[MSTCAP];
  __shared__ int c_m, c_np, c_hook, c_chg;
  __shared__ unsigned fminb, fmaxb;
  __shared__ int c_l2;

  int b = blockIdx.x;
  int tid = threadIdx.x;
  int lane = tid & 63;
  if (tid == 0) { c_m = 0; c_l2 = 0; c_np = 0; c_chg = 0; c_hook = 1; fminb = 0x7f800000u; fmaxb = 0u; }
  if (tid < 128) { smu[tid] = 3.0e38f; sminv[tid] = tid; mstlist[tid] = ~0ull; }

  // weight prefetch, vectorized (consumed at the end)
  if (tid < 625) ((float4*)sWg)[tid] = ((const float4*)Wg)[tid];
  if (tid < 125) ((float4*)sWfc)[tid] = ((const float4*)Wfc)[tid];
  if (tid < 50) sbg[tid] = bg[tid];
  if (tid >= 64 && tid < 74) sbfc[tid - 64] = bfc[tid - 64];

  // load f (float4), per-wave min/max
  {
    float4 v4 = ((const float4*)(fin + b * NPTS))[tid];
    ((float4*)sf)[tid] = v4;
    float lmin = fminf(fminf(v4.x, v4.y), fminf(v4.z, v4.w));
    float lmax = fmaxf(fmaxf(v4.x, v4.y), fmaxf(v4.z, v4.w));
    for (int m = 32; m >= 1; m >>= 1) {
      lmin = fminf(lmin, __shfl_xor(lmin, m));
      lmax = fmaxf(lmax, __shfl_xor(lmax, m));
    }
    if (lane == 0) {
      atomicMin(&fminb, __float_as_uint(lmin));
      atomicMax(&fmaxb, __float_as_uint(lmax));
    }
  }
  __syncthreads();

  // steepest-descent pointers
  int preg[4];
#pragma unroll 4
  for (int s = 0; s < 4; ++s) {
    int v = tid + s * 1024;
    int vi = v >> 6, vj = v & 63;
    float bf = sf[v]; int bi = v;
    if (vj > 0)  { float fn = sf[v - 1];  int n = v - 1;  if (fn < bf || (fn == bf && n < bi)) { bf = fn; bi = n; } }
    if (vj < 63) { float fn = sf[v + 1];  int n = v + 1;  if (fn < bf || (fn == bf && n < bi)) { bf = fn; bi = n; } }
    if (vi > 0)  { float fn = sf[v - 64]; int n = v - 64; if (fn < bf || (fn == bf && n < bi)) { bf = fn; bi = n; } }
    if (vi < 63) { float fn = sf[v + 64]; int n = v + 64; if (fn < bf || (fn == bf && n < bi)) { bf = fn; bi = n; } }
    srep[v] = bi;
    preg[s] = bi;
  }
  __syncthreads();

  // pointer jumping, double-hop, early-exit via round-stamped flag (benign same-value races)
  for (int it = 0; it < 8; ++it) {
    bool ch = false;
#pragma unroll 4
    for (int s = 0; s < 4; ++s) {
      int x = srep[preg[s]];
      x = srep[x];
      ch |= (x != preg[s]);
      srep[tid + s * 1024] = x;
      preg[s] = x;
    }
    u64 bl = __ballot(ch);
    if (lane == 0 && bl != 0ull) c_chg = it + 1;
    __syncthreads();
    if (c_chg != it + 1) break;   // nobody changed this round -> all at roots
  }

  // compact basin ids at minima
  for (int v = tid; v < NPTS; v += 1024) {
    if (srep[v] == v) {
      int id = atomicAdd(&c_m, 1);
      if (id < IDCAP) { sbasin[v] = id; smu[id] = sf[v]; sminv[id] = v; }
      else sbasin[v] = IDCAP - 1;
    }
  }
  __syncthreads();
  for (int v = tid; v < NPTS; v += 1024) {
    if (srep[v] != v) sbasin[v] = sbasin[srep[v]];
  }
  __syncthreads();   // srep dead

  // dedup via triangular pair table (aliases srep)
  unsigned* ptable = (unsigned*)srep;
  for (int i = tid; i < 4096; i += 1024) ptable[i] = 0xFFFFFFFFu;
  __syncthreads();
  for (int e = tid; e < NEDGE; e += 1024) {
    int u, v2;
    if (e < 4032) { int i = e / 63; int j = e - i * 63; u = (i << 6) | j; v2 = u + 1; }
    else          { int e2 = e - 4032; u = e2; v2 = u + 64; }
    int bu = sbasin[u], bv = sbasin[v2];
    if (bu != bv) {
      float wgt = fmaxf(sf[u], sf[v2]);
      int a = bu < bv ? bu : bv, bb2 = bu < bv ? bv : bu;
      int t = (bb2 * (bb2 - 1)) / 2 + a;
      atomicMin(&ptable[t], __float_as_uint(wgt));
    }
  }
  __syncthreads();   // sbasin dead

  // compact table -> slist2 (aliases sbasin): (w<<32) | (b<<8) | a
  u64* slist2 = (u64*)sbasin;
  for (int t = tid; t < 4096; t += 1024) {
    unsigned wv2 = ptable[t];
    if (wv2 != 0xFFFFFFFFu) {
      int bb2 = (int)((1.0f + sqrtf(1.0f + 8.0f * (float)t)) * 0.5f);
      while (bb2 > 1 && (bb2 * (bb2 - 1)) / 2 > t) bb2--;
      while (((bb2 + 1) * bb2) / 2 <= t) bb2++;
      int aa = t - (bb2 * (bb2 - 1)) / 2;
      int slot = atomicAdd(&c_l2, 1);
      if (slot < SORTCAP) slist2[slot] = ((u64)wv2 << 32) | (unsigned)((bb2 << 8) | aa);
    }
  }
  // pre-Boruvka init (comparr identity, minKey empty) fused with this barrier
  if (tid < 128) { comparr[tid] = tid; minKey[tid] = ~0ull; }
  __syncthreads();
  int n2 = c_l2; if (n2 > SORTCAP) n2 = SORTCAP;

  // ---- Boruvka contraction, 2 barriers/round; min-edge via u64 atomicMin on (w, edge_idx) ----
  int comp0 = lane, comp1 = 64 + lane;   // meaningful in wave0 only
  int nmst = 0;
  for (int round = 0; round < 7; ++round) {
    for (int e = tid; e < n2; e += 1024) {
      u64 ev = slist2[e];
      int a = (int)(ev & 0xffull), bb2 = (int)((ev >> 8) & 0xffull);
      int ra = comparr[a], rb = comparr[bb2];
      if (ra != rb) {
        u64 key = (ev & 0xFFFFFFFF00000000ull) | (u64)(unsigned)e;  // (w, idx): total order
        atomicMin(&minKey[ra], key);
        atomicMin(&minKey[rb], key);
      }
    }
    __syncthreads();
    if (tid < 64) {
      u64 k0 = minKey[lane], k1 = minKey[64 + lane];
      unsigned mi0 = (k0 != ~0ull) ? (unsigned)(k0 & 0xffffffffull) : 0xFFFFFFFFu;
      unsigned mi1 = (k1 != ~0ull) ? (unsigned)(k1 & 0xffffffffull) : 0xFFFFFFFFu;
      u64 ev0 = (mi0 != 0xFFFFFFFFu) ? slist2[mi0] : 0ull;
      u64 ev1 = (mi1 != 0xFFFFFFFFu) ? slist2[mi1] : 0ull;
      int a0 = (int)(ev0 & 0xffull), b0 = (int)((ev0 >> 8) & 0xffull);
      int a1 = (int)(ev1 & 0xffull), b1 = (int)((ev1 >> 8) & 0xffull);
      int raA = sel2(comp0, comp1, a0), rbA = sel2(comp0, comp1, b0);
      int raB = sel2(comp0, comp1, a1), rbB = sel2(comp0, comp1, b1);
      int parA0 = (mi0 != 0xFFFFFFFFu) ? ((raA == lane) ? rbA : raA) : lane;
      int parA1 = (mi1 != 0xFFFFFFFFu) ? ((raB == 64 + lane) ? rbB : raB) : (64 + lane);
      // 2-cycle resolve (distinct (w,idx) keys => only 2-cycles possible)
      int pp0 = sel2(parA0, parA1, parA0);
      int pp1 = sel2(parA0, parA1, parA1);
      int par0 = (pp0 == lane && lane < parA0) ? lane : parA0;
      int par1 = (pp1 == (64 + lane) && (64 + lane) < parA1) ? (64 + lane) : parA1;
      // collect MST edges: only hooking (non-root) endpoints collect -> each edge once, total <= IDCAP-1
      bool h0 = (par0 != lane);
      bool h1 = (par1 != (64 + lane));
      u64 mlo = __ballot(h0);
      int cnt0 = __popcll(mlo);
      int pos0 = nmst + __popcll(mlo & ((1ull << lane) - 1ull));
      if (h0 && pos0 < MSTCAP) mstlist[pos0] = ev0;
      u64 mhi = __ballot(h1);
      int pos1 = nmst + cnt0 + __popcll(mhi & ((1ull << lane) - 1ull));
      if (h1 && pos1 < MSTCAP) mstlist[pos1] = ev1;
      int tot = cnt0 + __popcll(mhi);
      nmst += tot;
      if (lane == 0) c_hook = (tot > 0);
      // compress par, then update comp; write comparr + re-init minKey for next round
      for (int j = 0; j < 7; ++j) {
        int n0 = sel2(par0, par1, par0);
        int n1 = sel2(par0, par1, par1);
        bool chp = (n0 != par0) || (n1 != par1);
        par0 = n0; par1 = n1;
        if (__ballot(chp) == 0ull) break;
      }
      comp0 = sel2(par0, par1, comp0);
      comp1 = sel2(par0, par1, comp1);
      comparr[lane] = comp0; comparr[64 + lane] = comp1;
      minKey[lane] = ~0ull; minKey[64 + lane] = ~0ull;
    }
    __syncthreads();
    if (c_hook == 0) break;
  }
  if (nmst > MSTCAP) nmst = MSTCAP;

  // ---- wave0: in-register sort (N=128, 2 regs, zero barriers) + packed-state readlane Kruskal ----
  if (tid < 64) {
    u64 e0 = mstlist[lane], e1 = mstlist[64 + lane];
    ALL2(1,2)
    ALL2(2,4) ALL2(1,4)
    ALL2(4,8) ALL2(2,8) ALL2(1,8)
    ALL2(8,16) ALL2(4,16) ALL2(2,16) ALL2(1,16)
    ALL2(16,32) ALL2(8,32) ALL2(4,32) ALL2(2,32) ALL2(1,32)
    ALL2(32,64) ALL2(16,64) ALL2(8,64) ALL2(4,64) ALL2(2,64) ALL2(1,64)
    CXR(0,1,128)
    ALL2(32,128) ALL2(16,128) ALL2(8,128) ALL2(4,128) ALL2(2,128) ALL2(1,128)

    // packed union-find state per id: (mu_bits<<32) | (rv<<13) | p
    u64 st0 = ((u64)__float_as_uint(smu[lane]) << 32) | ((u64)(unsigned)sminv[lane] << 13) | (unsigned)lane;
    u64 st1 = ((u64)__float_as_uint(smu[64 + lane]) << 32) | ((u64)(unsigned)sminv[64 + lane] << 13) | (unsigned)(64 + lane);
    int np = 0;
#define KBLK(R, BASE) \
    for (int s = 0; s < 64; ++s) { \
      if (BASE + s >= nmst) break; \
      u64 ev = rdl64(e##R, s); \
      int a = (int)(ev & 0xffull), bb2 = (int)((ev >> 8) & 0xffull); \
      int ia = a & 63, ib = bb2 & 63; \
      u64 stA = (a < 64) ? rdl64(st0, ia) : rdl64(st1, ia); \
      u64 stB = (bb2 < 64) ? rdl64(st0, ib) : rdl64(st1, ib); \
      int pa = (int)(stA & 127ull), pb = (int)(stB & 127ull); \
      if (pa == pb) continue; \
      bool aeld = (stA >> 13) < (stB >> 13); \
      u64 stE = aeld ? stA : stB; \
      u64 stY = aeld ? stB : stA; \
      unsigned yng = (unsigned)(stY & 127ull); \
      float byoung = __uint_as_float((unsigned)(stY >> 32)); \
      bool g0 = ((unsigned)(st0 & 127ull) == yng); st0 = g0 ? stE : st0; \
      bool g1 = ((unsigned)(st1 & 127ull) == yng); st1 = g1 ? stE : st1; \
      if (lane == 0 && np < PAIRCAP - 1) spairs[np] = make_float2(byoung, __uint_as_float((unsigned)(ev >> 32))); \
      np++; \
    }
    KBLK(0, 0) KBLK(1, 64)
#undef KBLK
    if (np > PAIRCAP - 1) np = PAIRCAP - 1;
    if (lane == 0) {
      spairs[np] = make_float2(__uint_as_float(fminb), __uint_as_float(fmaxb));  // essential pair
      c_np = np + 1;
    }
  }
  __syncthreads();

  // landscape (top-2 triangles at 25 t's)
  int totp = c_np;
  if (tid < 25) {
    float tv = 1.875f * (float)tid;
    float top1 = 0.f, top2 = 0.f;
    for (int i = 0; i < totp; ++i) {
      float2 p = spairs[i];
      float tri = fminf(tv - p.x, p.y - tv);
      tri = fmaxf(tri, 0.f);
      if (tri > top1) { top2 = top1; top1 = tri; }
      else if (tri > top2) top2 = tri;
    }
    sland[tid] = top1;
    sland[25 + tid] = top2;
  }
  __syncthreads();

  // x = land @ Wg.T + bg
  if (tid < 50) {
    float acc = sbg[tid];
    for (int k = 0; k < 50; ++k) acc += sland[k] * sWg[tid * 50 + k];
    sx[tid] = acc;
  }
  __syncthreads();

  // outputs
  if (tid < 50) atomicAdd(&out[20 + tid], fabsf(sx[tid]));
  if (tid >= 64 && tid < 74) {
    int c = tid - 64;
    float acc = sbfc[c];
    for (int o = 0; o < 50; ++o) acc += fmaxf(sx[o], 0.f) * sWfc[c * 50 + o];
    out[b * 10 + c] = acc;
  }
}

extern "C" void kernel_launch(void* const* d_in, const int* in_sizes, int n_in,
                              void* d_out, int out_size, void* d_ws, size_t ws_size,
                              hipStream_t stream) {
  (void)in_sizes; (void)n_in; (void)out_size; (void)ws_size;
  const float* input = (const float*)d_in[0];
  const float* Wg  = (const float*)d_in[1];
  const float* bg  = (const float*)d_in[2];
  const float* Wfc = (const float*)d_in[3];
  const float* bfc = (const float*)d_in[4];
  float* out = (float*)d_out;

  float* f_ws = (float*)d_ws;  // 2*4096 f32

  dtm_kernel<<<dim3(256, 2), 1024, 0, stream>>>(input, f_ws, out);
  ph_fused<<<dim3(2), 1024, 0, stream>>>(f_ws, Wg, bg, Wfc, bfc, out);
}

// Round 22
// 54.421 us; speedup vs baseline: 1.6486x; 1.0210x over previous
//
#include <hip/hip_runtime.h>

#define NPTS 4096
#define NEDGE 8064
#define M0f 0.05f
#define KMAXD2 7938
#define IDCAP 90          // basin-id clamp; triangular pair table needs IDCAP*(IDCAP-1)/2 <= 4096
#define SORTCAP 512
#define PAIRCAP 160
#define MSTCAP 128        // collected edges = #merges <= IDCAP-1 = 89 (distinct; mutual-min collects once)

typedef unsigned long long u64;

__device__ inline float waveSum(float x) {
  for (int m = 32; m >= 1; m >>= 1) x += __shfl_xor(x, m);
  return x;
}

__device__ inline int isqrt_i(int x) {  // exact floor sqrt for 0 <= x < 2^20
  int r = (int)sqrtf((float)x);
  if ((r + 1) * (r + 1) <= x) r++;
  else if (r * r > x) r--;
  return r;
}

// uniform-index readlane helpers
__device__ inline int rdl(int v, int l) { return __builtin_amdgcn_readlane(v, l); }
__device__ inline u64 rdl64(u64 x, int l) {
  unsigned lo = (unsigned)__builtin_amdgcn_readlane((int)(unsigned)(x & 0xffffffffull), l);
  unsigned hi = (unsigned)__builtin_amdgcn_readlane((int)(unsigned)(x >> 32), l);
  return ((u64)hi << 32) | (u64)lo;
}
// dynamic select from a 128-entry register file split across wave (v0: ids 0-63, v1: 64-127)
__device__ inline int sel2(int v0, int v1, int idx) {
  int x0 = __shfl(v0, idx & 63);
  int x1 = __shfl(v1, idx & 63);
  return (idx < 64) ? x0 : x1;
}
__device__ inline u64 shfl_xor64(u64 x, int m) {
  int lo = __shfl_xor((int)(unsigned)(x & 0xffffffffull), m);
  int hi = __shfl_xor((int)(unsigned)(x >> 32), m);
  return ((u64)(unsigned)hi << 32) | (u64)(unsigned)lo;
}

// in-wave bitonic compare-exchange (element i = R*64 + lane), N=128 over 2 regs
#define CXL(R, J, K) { \
  u64 vo = shfl_xor64(e##R, J); \
  bool up = (((((R) * 64) & (K)) | (lane & (K))) == 0); \
  bool lower = ((lane & (J)) == 0); \
  bool kmin = (lower == up); \
  u64 mn = (e##R < vo) ? e##R : vo; \
  u64 mx = (e##R < vo) ? vo : e##R; \
  e##R = kmin ? mn : mx; }
#define ALL2(J, K) CXL(0,J,K) CXL(1,J,K)
#define CXR(RA, RB, K) { \
  const bool up = ((((RA) * 64) & (K)) == 0); \
  u64 va = e##RA, vb = e##RB; \
  u64 mn = (va < vb) ? va : vb; \
  u64 mx = (va < vb) ? vb : va; \
  e##RA = up ? mn : mx; e##RB = up ? mx : mn; }

// ---------------- Kernel 1: DTM (hybrid interpolation search) + out-zero ----------------
__global__ __launch_bounds__(1024) void dtm_kernel(const float* __restrict__ win,
                                                   float* __restrict__ fout,
                                                   float* __restrict__ out) {
  __shared__ float P0[64][65];
  __shared__ float P1[64][65];
  __shared__ float P2[64][65];
  int b = blockIdx.y;
  const float* w = win + b * NPTS;
  int tid = threadIdx.x, lane = tid & 63, wv = tid >> 6;

  if (blockIdx.x == 0 && blockIdx.y == 0 && tid < 50) out[20 + tid] = 0.f;  // signal accum base

  for (int rr = 0; rr < 4; ++rr) {
    int r = (wv << 2) | rr;
    float x0 = w[(r << 6) | lane];
    float fl = (float)lane;
    float x1 = x0 * fl, x2 = x1 * fl;
    for (int d = 1; d < 64; d <<= 1) {
      float t0 = __shfl_up(x0, d);
      float t1 = __shfl_up(x1, d);
      float t2 = __shfl_up(x2, d);
      if (lane >= d) { x0 += t0; x1 += t1; x2 += t2; }
    }
    P0[r][lane] = x0; P1[r][lane] = x1; P2[r][lane] = x2;
  }
  __syncthreads();

  float sumw = waveSum(P0[lane][63]);
  float thr = M0f * sumw;

  int q = blockIdx.x * 16 + wv;
  int qi = q >> 6, qj = q & 63;
  int di = qi - lane;
  int disq = di * di;

  auto evalF = [&](int K) -> float {
    float s0 = 0.f;
    int rem = K - disq;
    if (rem >= 0) {
      int r = isqrt_i(rem);
      int l0 = qj - r; l0 = l0 < 0 ? 0 : l0;
      int h0 = qj + r; h0 = h0 > 63 ? 63 : h0;
      s0 = P0[lane][h0] - (l0 > 0 ? P0[lane][l0 - 1] : 0.f);
    }
    return waveSum(s0);
  };

  // hybrid interpolation/bisection: invariant Flo < thr <= Fhi; bisect every 2nd probe
  int lo = -1, hi = KMAXD2;
  float Flo = 0.f, Fhi = sumw;
  int itc = 0;
  while (hi - lo > 1 && itc < 40) {
    int mid;
    if (itc & 1) {
      mid = (lo + hi) >> 1;
    } else {
      float t = (thr - Flo) / fmaxf(Fhi - Flo, 1e-30f);
      mid = lo + (int)(t * (float)(hi - lo));
      mid = mid < lo + 1 ? lo + 1 : (mid > hi - 1 ? hi - 1 : mid);
    }
    float F = evalF(mid);
    if (F >= thr) { hi = mid; Fhi = F; } else { lo = mid; Flo = F; }
    ++itc;
  }
  int kstar = hi;
  float Fm = Flo;

  float g = 0.f;
  {
    int rem = (kstar - 1) - disq;
    if (rem >= 0) {
      int r = isqrt_i(rem);
      int l0 = qj - r; l0 = l0 < 0 ? 0 : l0;
      int h0 = qj + r; h0 = h0 > 63 ? 63 : h0;
      float S0 = P0[lane][h0] - (l0 > 0 ? P0[lane][l0 - 1] : 0.f);
      float S1 = P1[lane][h0] - (l0 > 0 ? P1[lane][l0 - 1] : 0.f);
      float S2 = P2[lane][h0] - (l0 > 0 ? P2[lane][l0 - 1] : 0.f);
      float fq = (float)qj;
      g = (float)disq * S0 + fq * fq * S0 - 2.f * fq * S1 + S2;
    }
  }
  float G = waveSum(g);
  float val = (G + (thr - Fm) * (float)kstar) / thr;
  val = val < 0.f ? 0.f : val;
  float res = (224.f / 63.f) * sqrtf(val);
  if (lane == 0) fout[b * NPTS + q] = res;
}

// ---------------- Kernel 2: fused PH0 (wave0 Boruvka) + landscape + MLP ----------------
__global__ __launch_bounds__(1024) void ph_fused(const float* __restrict__ fin,
                                                 const float* __restrict__ Wg,
                                                 const float* __restrict__ bg,
                                                 const float* __restrict__ Wfc,
                                                 const float* __restrict__ bfc,
                                                 float* __restrict__ out) {
  __shared__ __align__(16) float sf[NPTS];
  __shared__ __align__(16) int srep[NPTS];    // aliased later: unsigned ptable[4096]
  __shared__ __align__(16) int sbasin[NPTS];  // aliased later: u64 slist2[SORTCAP]
  __shared__ float smu[128];
  __shared__ int sminv[128];
  __shared__ float2 spairs[PAIRCAP];
  __shared__ float sland[50];
  __shared__ float sx[50];
  __shared__ __align__(16) float sWg[2500];
  __shared__ float sbg[50];
  __shared__ __align__(16) float sWfc[500];
  __shared__ float sbfc[10];
  __shared__ u64 minKey[128];
  __shared__ u64 mstlist[MSTCAP];
  __shared__ int c_m, c_np, c_chg;
  __shared__ unsigned fminb, fmaxb;
  __shared__ int c_l2;

  int b = blockIdx.x;
  int tid = threadIdx.x;
  int lane = tid & 63;
  if (tid == 0) { c_m = 0; c_l2 = 0; c_np = 0; c_chg = 0; fminb = 0x7f800000u; fmaxb = 0u; }
  if (tid < 128) { smu[tid] = 3.0e38f; sminv[tid] = tid; mstlist[tid] = ~0ull; }

  // weight prefetch, vectorized (consumed at the end)
  if (tid < 625) ((float4*)sWg)[tid] = ((const float4*)Wg)[tid];
  if (tid < 125) ((float4*)sWfc)[tid] = ((const float4*)Wfc)[tid];
  if (tid < 50) sbg[tid] = bg[tid];
  if (tid >= 64 && tid < 74) sbfc[tid - 64] = bfc[tid - 64];

  // load f (float4), per-wave min/max
  {
    float4 v4 = ((const float4*)(fin + b * NPTS))[tid];
    ((float4*)sf)[tid] = v4;
    float lmin = fminf(fminf(v4.x, v4.y), fminf(v4.z, v4.w));
    float lmax = fmaxf(fmaxf(v4.x, v4.y), fmaxf(v4.z, v4.w));
    for (int m = 32; m >= 1; m >>= 1) {
      lmin = fminf(lmin, __shfl_xor(lmin, m));
      lmax = fmaxf(lmax, __shfl_xor(lmax, m));
    }
    if (lane == 0) {
      atomicMin(&fminb, __float_as_uint(lmin));
      atomicMax(&fmaxb, __float_as_uint(lmax));
    }
  }
  __syncthreads();

  // steepest-descent pointers
  int preg[4];
#pragma unroll 4
  for (int s = 0; s < 4; ++s) {
    int v = tid + s * 1024;
    int vi = v >> 6, vj = v & 63;
    float bf = sf[v]; int bi = v;
    if (vj > 0)  { float fn = sf[v - 1];  int n = v - 1;  if (fn < bf || (fn == bf && n < bi)) { bf = fn; bi = n; } }
    if (vj < 63) { float fn = sf[v + 1];  int n = v + 1;  if (fn < bf || (fn == bf && n < bi)) { bf = fn; bi = n; } }
    if (vi > 0)  { float fn = sf[v - 64]; int n = v - 64; if (fn < bf || (fn == bf && n < bi)) { bf = fn; bi = n; } }
    if (vi < 63) { float fn = sf[v + 64]; int n = v + 64; if (fn < bf || (fn == bf && n < bi)) { bf = fn; bi = n; } }
    srep[v] = bi;
    preg[s] = bi;
  }
  __syncthreads();

  // pointer jumping, double-hop, early-exit via round-stamped flag (benign same-value races)
  for (int it = 0; it < 8; ++it) {
    bool ch = false;
#pragma unroll 4
    for (int s = 0; s < 4; ++s) {
      int x = srep[preg[s]];
      x = srep[x];
      ch |= (x != preg[s]);
      srep[tid + s * 1024] = x;
      preg[s] = x;
    }
    u64 bl = __ballot(ch);
    if (lane == 0 && bl != 0ull) c_chg = it + 1;
    __syncthreads();
    if (c_chg != it + 1) break;   // nobody changed this round -> all at roots
  }

  // compact basin ids at minima
  for (int v = tid; v < NPTS; v += 1024) {
    if (srep[v] == v) {
      int id = atomicAdd(&c_m, 1);
      if (id < IDCAP) { sbasin[v] = id; smu[id] = sf[v]; sminv[id] = v; }
      else sbasin[v] = IDCAP - 1;
    }
  }
  __syncthreads();
  for (int v = tid; v < NPTS; v += 1024) {
    if (srep[v] != v) sbasin[v] = sbasin[srep[v]];
  }
  __syncthreads();   // srep dead

  // dedup via triangular pair table (aliases srep)
  unsigned* ptable = (unsigned*)srep;
  for (int i = tid; i < 4096; i += 1024) ptable[i] = 0xFFFFFFFFu;
  __syncthreads();
  for (int e = tid; e < NEDGE; e += 1024) {
    int u, v2;
    if (e < 4032) { int i = e / 63; int j = e - i * 63; u = (i << 6) | j; v2 = u + 1; }
    else          { int e2 = e - 4032; u = e2; v2 = u + 64; }
    int bu = sbasin[u], bv = sbasin[v2];
    if (bu != bv) {
      float wgt = fmaxf(sf[u], sf[v2]);
      int a = bu < bv ? bu : bv, bb2 = bu < bv ? bv : bu;
      int t = (bb2 * (bb2 - 1)) / 2 + a;
      atomicMin(&ptable[t], __float_as_uint(wgt));
    }
  }
  __syncthreads();   // sbasin dead

  // compact table -> slist2 (aliases sbasin): (w<<32) | (b<<8) | a
  u64* slist2 = (u64*)sbasin;
  for (int t = tid; t < 4096; t += 1024) {
    unsigned wv2 = ptable[t];
    if (wv2 != 0xFFFFFFFFu) {
      int bb2 = (int)((1.0f + sqrtf(1.0f + 8.0f * (float)t)) * 0.5f);
      while (bb2 > 1 && (bb2 * (bb2 - 1)) / 2 > t) bb2--;
      while (((bb2 + 1) * bb2) / 2 <= t) bb2++;
      int aa = t - (bb2 * (bb2 - 1)) / 2;
      int slot = atomicAdd(&c_l2, 1);
      if (slot < SORTCAP) slist2[slot] = ((u64)wv2 << 32) | (unsigned)((bb2 << 8) | aa);
    }
  }
  __syncthreads();
  int n2 = c_l2; if (n2 > SORTCAP) n2 = SORTCAP;

  // ---- wave0-only: Boruvka (zero barriers) + in-register sort + packed-state Kruskal ----
  if (tid < 64) {
    // edges into registers: 8 u64/lane covers SORTCAP=512
    u64 Ea[8];
#pragma unroll
    for (int k = 0; k < 8; ++k) {
      int idx = lane + (k << 6);
      Ea[k] = (idx < n2) ? slist2[idx] : ~0ull;
    }
    int comp0 = lane, comp1 = 64 + lane;
    int nmst = 0;
    for (int round = 0; round < 7; ++round) {
      minKey[lane] = ~0ull; minKey[64 + lane] = ~0ull;   // same-wave LDS ordering
      int anyact = 0;
#pragma unroll
      for (int k = 0; k < 8; ++k) {
        u64 ev = Ea[k];
        if (ev != ~0ull) {
          int a = (int)(ev & 0xffull), bb2 = (int)((ev >> 8) & 0xffull);
          int ra = sel2(comp0, comp1, a);
          int rb = sel2(comp0, comp1, bb2);
          if (ra != rb) {
            u64 key = (ev & 0xFFFFFFFF00000000ull) | (u64)(unsigned)(lane + (k << 6));
            atomicMin(&minKey[ra], key);
            atomicMin(&minKey[rb], key);
            anyact = 1;
          }
        }
      }
      if (__ballot(anyact) == 0ull) break;   // no active edge -> contraction complete
      u64 k0 = minKey[lane], k1 = minKey[64 + lane];
      unsigned mi0 = (k0 != ~0ull) ? (unsigned)(k0 & 0xffffffffull) : 0xFFFFFFFFu;
      unsigned mi1 = (k1 != ~0ull) ? (unsigned)(k1 & 0xffffffffull) : 0xFFFFFFFFu;
      u64 ev0 = (mi0 != 0xFFFFFFFFu) ? slist2[mi0] : 0ull;
      u64 ev1 = (mi1 != 0xFFFFFFFFu) ? slist2[mi1] : 0ull;
      int a0 = (int)(ev0 & 0xffull), b0 = (int)((ev0 >> 8) & 0xffull);
      int a1 = (int)(ev1 & 0xffull), b1 = (int)((ev1 >> 8) & 0xffull);
      int raA = sel2(comp0, comp1, a0), rbA = sel2(comp0, comp1, b0);
      int raB = sel2(comp0, comp1, a1), rbB = sel2(comp0, comp1, b1);
      int parA0 = (mi0 != 0xFFFFFFFFu) ? ((raA == lane) ? rbA : raA) : lane;
      int parA1 = (mi1 != 0xFFFFFFFFu) ? ((raB == 64 + lane) ? rbB : raB) : (64 + lane);
      // 2-cycle resolve (distinct (w,idx) keys => only 2-cycles possible)
      int pp0 = sel2(parA0, parA1, parA0);
      int pp1 = sel2(parA0, parA1, parA1);
      int par0 = (pp0 == lane && lane < parA0) ? lane : parA0;
      int par1 = (pp1 == (64 + lane) && (64 + lane) < parA1) ? (64 + lane) : parA1;
      // collect MST edges: only hooking (non-root) endpoints collect -> each edge once, total <= IDCAP-1
      bool h0 = (par0 != lane);
      bool h1 = (par1 != (64 + lane));
      u64 mlo = __ballot(h0);
      int cnt0 = __popcll(mlo);
      int pos0 = nmst + __popcll(mlo & ((1ull << lane) - 1ull));
      if (h0 && pos0 < MSTCAP) mstlist[pos0] = ev0;
      u64 mhi = __ballot(h1);
      int pos1 = nmst + cnt0 + __popcll(mhi & ((1ull << lane) - 1ull));
      if (h1 && pos1 < MSTCAP) mstlist[pos1] = ev1;
      nmst += cnt0 + __popcll(mhi);
      // compress par, then update comp
      for (int j = 0; j < 7; ++j) {
        int n0 = sel2(par0, par1, par0);
        int n1 = sel2(par0, par1, par1);
        bool chp = (n0 != par0) || (n1 != par1);
        par0 = n0; par1 = n1;
        if (__ballot(chp) == 0ull) break;
      }
      comp0 = sel2(par0, par1, comp0);
      comp1 = sel2(par0, par1, comp1);
    }
    if (nmst > MSTCAP) nmst = MSTCAP;

    // in-register sort (N=128, 2 regs, zero barriers)
    u64 e0 = mstlist[lane], e1 = mstlist[64 + lane];
    ALL2(1,2)
    ALL2(2,4) ALL2(1,4)
    ALL2(4,8) ALL2(2,8) ALL2(1,8)
    ALL2(8,16) ALL2(4,16) ALL2(2,16) ALL2(1,16)
    ALL2(16,32) ALL2(8,32) ALL2(4,32) ALL2(2,32) ALL2(1,32)
    ALL2(32,64) ALL2(16,64) ALL2(8,64) ALL2(4,64) ALL2(2,64) ALL2(1,64)
    CXR(0,1,128)
    ALL2(32,128) ALL2(16,128) ALL2(8,128) ALL2(4,128) ALL2(2,128) ALL2(1,128)

    // packed union-find state per id: (mu_bits<<32) | (rv<<13) | p
    u64 st0 = ((u64)__float_as_uint(smu[lane]) << 32) | ((u64)(unsigned)sminv[lane] << 13) | (unsigned)lane;
    u64 st1 = ((u64)__float_as_uint(smu[64 + lane]) << 32) | ((u64)(unsigned)sminv[64 + lane] << 13) | (unsigned)(64 + lane);
    int np = 0;
#define KBLK(R, BASE) \
    for (int s = 0; s < 64; ++s) { \
      if (BASE + s >= nmst) break; \
      u64 ev = rdl64(e##R, s); \
      int a = (int)(ev & 0xffull), bb2 = (int)((ev >> 8) & 0xffull); \
      int ia = a & 63, ib = bb2 & 63; \
      u64 stA = (a < 64) ? rdl64(st0, ia) : rdl64(st1, ia); \
      u64 stB = (bb2 < 64) ? rdl64(st0, ib) : rdl64(st1, ib); \
      int pa = (int)(stA & 127ull), pb = (int)(stB & 127ull); \
      if (pa == pb) continue; \
      bool aeld = (stA >> 13) < (stB >> 13); \
      u64 stE = aeld ? stA : stB; \
      u64 stY = aeld ? stB : stA; \
      unsigned yng = (unsigned)(stY & 127ull); \
      float byoung = __uint_as_float((unsigned)(stY >> 32)); \
      bool g0 = ((unsigned)(st0 & 127ull) == yng); st0 = g0 ? stE : st0; \
      bool g1 = ((unsigned)(st1 & 127ull) == yng); st1 = g1 ? stE : st1; \
      if (lane == 0 && np < PAIRCAP - 1) spairs[np] = make_float2(byoung, __uint_as_float((unsigned)(ev >> 32))); \
      np++; \
    }
    KBLK(0, 0) KBLK(1, 64)
#undef KBLK
    if (np > PAIRCAP - 1) np = PAIRCAP - 1;
    if (lane == 0) {
      spairs[np] = make_float2(__uint_as_float(fminb), __uint_as_float(fmaxb));  // essential pair
      c_np = np + 1;
    }
  }
  __syncthreads();

  // landscape (top-2 triangles at 25 t's)
  int totp = c_np;
  if (tid < 25) {
    float tv = 1.875f * (float)tid;
    float top1 = 0.f, top2 = 0.f;
    for (int i = 0; i < totp; ++i) {
      float2 p = spairs[i];
      float tri = fminf(tv - p.x, p.y - tv);
      tri = fmaxf(tri, 0.f);
      if (tri > top1) { top2 = top1; top1 = tri; }
      else if (tri > top2) top2 = tri;
    }
    sland[tid] = top1;
    sland[25 + tid] = top2;
  }
  __syncthreads();

  // x = land @ Wg.T + bg
  if (tid < 50) {
    float acc = sbg[tid];
    for (int k = 0; k < 50; ++k) acc += sland[k] * sWg[tid * 50 + k];
    sx[tid] = acc;
  }
  __syncthreads();

  // outputs
  if (tid < 50) atomicAdd(&out[20 + tid], fabsf(sx[tid]));
  if (tid >= 64 && tid < 74) {
    int c = tid - 64;
    float acc = sbfc[c];
    for (int o = 0; o < 50; ++o) acc += fmaxf(sx[o], 0.f) * sWfc[c * 50 + o];
    out[b * 10 + c] = acc;
  }
}

extern "C" void kernel_launch(void* const* d_in, const int* in_sizes, int n_in,
                              void* d_out, int out_size, void* d_ws, size_t ws_size,
                              hipStream_t stream) {
  (void)in_sizes; (void)n_in; (void)out_size; (void)ws_size;
  const float* input = (const float*)d_in[0];
  const float* Wg  = (const float*)d_in[1];
  const float* bg  = (const float*)d_in[2];
  const float* Wfc = (const float*)d_in[3];
  const float* bfc = (const float*)d_in[4];
  float* out = (float*)d_out;

  float* f_ws = (float*)d_ws;  // 2*4096 f32

  dtm_kernel<<<dim3(256, 2), 1024, 0, stream>>>(input, f_ws, out);
  ph_fused<<<dim3(2), 1024, 0, stream>>>(f_ws, Wg, bg, Wfc, bfc, out);
}